// Round 1
// baseline (10539.939 us; speedup 1.0000x reference)
//
#include <hip/hip_runtime.h>
#include <math.h>

#define S   2048
#define E   4096
#define H   32
#define HD  128
#define NKEEP 205
#define NEGF -3.0e38f

__device__ __forceinline__ unsigned fmap(float x) {
    unsigned u = __float_as_uint(x);
    return (u & 0x80000000u) ? ~u : (u | 0x80000000u);
}

// ---------------------------------------------------------------------------
// fp32 tiled GEMM: C[M,N] = A[M,K] @ B[K,N], all row-major. M=2048,N=4096,K=4096.
// 128x128 block tile, BK=8, 8x8 microtile, 256 threads.
// ---------------------------------------------------------------------------
__global__ __launch_bounds__(256) void gemm_fp32(const float* __restrict__ A,
                                                 const float* __restrict__ B,
                                                 float* __restrict__ C,
                                                 int M, int N, int Kd)
{
    __shared__ float As[8][132];
    __shared__ float Bs[8][132];
    const int tid = threadIdx.x;
    const int tx = tid & 15, ty = tid >> 4;
    const int bm = blockIdx.y, bn = blockIdx.x;
    const int arow = tid >> 1, ac4 = (tid & 1) * 4;
    const int brow = tid >> 5, bc4 = (tid & 31) * 4;
    const float* Ap = A + (size_t)(bm * 128 + arow) * Kd + ac4;
    const float* Bp = B + (size_t)brow * N + bn * 128 + bc4;

    float acc[8][8];
#pragma unroll
    for (int i = 0; i < 8; i++)
#pragma unroll
        for (int j = 0; j < 8; j++) acc[i][j] = 0.f;

    for (int k0 = 0; k0 < Kd; k0 += 8) {
        float4 av = *(const float4*)(Ap + k0);
        float4 bv = *(const float4*)(Bp + (size_t)k0 * N);
        __syncthreads();
        As[ac4 + 0][arow] = av.x;
        As[ac4 + 1][arow] = av.y;
        As[ac4 + 2][arow] = av.z;
        As[ac4 + 3][arow] = av.w;
        *(float4*)&Bs[brow][bc4] = bv;
        __syncthreads();
#pragma unroll
        for (int kk = 0; kk < 8; kk++) {
            float a[8], b[8];
            *(float4*)&a[0] = *(const float4*)&As[kk][ty * 8];
            *(float4*)&a[4] = *(const float4*)&As[kk][ty * 8 + 4];
            *(float4*)&b[0] = *(const float4*)&Bs[kk][tx * 8];
            *(float4*)&b[4] = *(const float4*)&Bs[kk][tx * 8 + 4];
#pragma unroll
            for (int i = 0; i < 8; i++)
#pragma unroll
                for (int j = 0; j < 8; j++)
                    acc[i][j] += a[i] * b[j];
        }
    }
    const size_t row0 = bm * 128 + ty * 8;
    const size_t col0 = bn * 128 + tx * 8;
#pragma unroll
    for (int i = 0; i < 8; i++) {
        *(float4*)&C[(row0 + i) * N + col0]     = make_float4(acc[i][0], acc[i][1], acc[i][2], acc[i][3]);
        *(float4*)&C[(row0 + i) * N + col0 + 4] = make_float4(acc[i][4], acc[i][5], acc[i][6], acc[i][7]);
    }
}

// ---------------------------------------------------------------------------
// RoPE: QR/KR[s][h*128+d] from Q/K. One thread per (s,h,d<64) pair.
// ---------------------------------------------------------------------------
__global__ __launch_bounds__(256) void rope_kernel(const float* __restrict__ Q,
                                                   const float* __restrict__ K,
                                                   float* __restrict__ QR,
                                                   float* __restrict__ KR)
{
    int idx = blockIdx.x * 256 + threadIdx.x;   // 0 .. S*H*64-1 (= S*2048)
    int s   = idx >> 11;
    int rem = idx & 2047;
    int h   = rem >> 6;
    int d   = rem & 63;
    float inv = powf(10000.0f, -(float)d * (1.0f / 64.0f));
    float ang = (float)s * inv;
    float sn, cs;
    sincosf(ang, &sn, &cs);
    size_t base = (size_t)s * E + h * HD;
    float q0 = Q[base + d], q1 = Q[base + d + 64];
    QR[base + d]      = q0 * cs - q1 * sn;
    QR[base + d + 64] = q1 * cs + q0 * sn;
    float k0 = K[base + d], k1 = K[base + d + 64];
    KR[base + d]      = k0 * cs - k1 * sn;
    KR[base + d + 64] = k1 * cs + k0 * sn;
}

// ---------------------------------------------------------------------------
// Selection: per (head, 7-query-row tile) block. Computes fp32 draft scores
// (pre-RoPE q.k) into LDS, exact radix-select of 205th-largest per row,
// writes keep-mask bits (causal+sparse combined) to global.
// Dynamic LDS: scores 7*2048 f32 + qtile 7*128 f32 + 2x256 u32 hist = 62976 B.
// ---------------------------------------------------------------------------
__global__ __launch_bounds__(256) void select_kernel(const float* __restrict__ Q,
                                                     const float* __restrict__ K,
                                                     unsigned* __restrict__ Mask)
{
    extern __shared__ float smem[];
    float* scores   = smem;                 // 7*2048
    float* qtile    = smem + 7 * 2048;      // 7*128
    unsigned* hist  = (unsigned*)(qtile + 7 * 128);   // 256
    unsigned* hist2 = hist + 256;                     // 256
    __shared__ unsigned sh_prefix, sh_need;

    const int q0 = blockIdx.x * 7;
    const int h  = blockIdx.y;
    const int tid = threadIdx.x;

    if (tid < 224) {
        int row = tid >> 5, c4 = (tid & 31) * 4;
        if (q0 + row < S)
            *(float4*)&qtile[row * 128 + c4] =
                *(const float4*)&Q[(size_t)(q0 + row) * E + h * HD + c4];
    }
    for (int i = tid; i < 7 * 2048; i += 256) scores[i] = NEGF;
    __syncthreads();

    // --- draft scores: thread (c=tid&31, r=tid>>5) computes row r, col cb+c
    {
        const int c = tid & 31, r = tid >> 5;
        const int qg = q0 + r;
        const bool active = (r < 7) && (qg < S);
        const int kend = min(q0 + 7, S);
        for (int cb = 0; cb < kend; cb += 32) {
            int col = cb + c;
            if (active) {
                const float* kp = &K[(size_t)col * E + h * HD];
                const float* qp = &qtile[r * 128];
                float acc = 0.f;
#pragma unroll 4
                for (int d = 0; d < 128; d += 4) {
                    float4 kv = *(const float4*)(kp + d);
                    float4 qv = *(const float4*)(qp + d);
                    acc += qv.x * kv.x + qv.y * kv.y + qv.z * kv.z + qv.w * kv.w;
                }
                scores[r * 2048 + col] = (col <= qg) ? acc : NEGF;
            }
        }
    }
    __syncthreads();

    // --- per-row exact radix select (4 passes of 8 bits) + mask write
    for (int rr = 0; rr < 7; rr++) {
        int qrow = q0 + rr;
        if (qrow >= S) break;
        int Vn = qrow + 1;
        bool full = (Vn <= NKEEP);
        unsigned thr_u = 0u;
        if (!full) {
            if (tid == 0) { sh_prefix = 0u; sh_need = NKEEP; }
            __syncthreads();
            for (int p = 0; p < 4; p++) {
                int shft = 24 - 8 * p;
                hist[tid] = 0u;
                __syncthreads();
                unsigned pref = sh_prefix;
                unsigned need = sh_need;
#pragma unroll
                for (int i = 0; i < 8; i++) {
                    int cc = tid + (i << 8);
                    unsigned u = fmap(scores[rr * 2048 + cc]);
                    bool part = (p == 0) || ((u >> (shft + 8)) == pref);
                    if (part) atomicAdd(&hist[(u >> shft) & 255u], 1u);
                }
                __syncthreads();
                // inclusive suffix-sum over 256 bins (Kogge-Stone, double buffer)
                unsigned* src = hist;
                unsigned* dst = hist2;
                for (int off = 1; off < 256; off <<= 1) {
                    unsigned add = (tid + off < 256) ? src[tid + off] : 0u;
                    unsigned me  = src[tid];
                    dst[tid] = me + add;
                    __syncthreads();
                    unsigned* t = src; src = dst; dst = t;
                }
                unsigned suf_b  = src[tid];
                unsigned suf_b1 = (tid < 255) ? src[tid + 1] : 0u;
                if (need > suf_b1 && need <= suf_b) {
                    sh_prefix = (pref << 8) | (unsigned)tid;
                    sh_need   = need - suf_b1;
                }
                __syncthreads();
            }
            thr_u = sh_prefix;  // bit pattern of the 205th-largest score
        }
        // mask bits via ballot: one 64-bit mask per wave iteration
        int lane = tid & 63, wv = tid >> 6;
        for (int base = wv * 64; base < S; base += 256) {
            int cc = base + lane;
            bool keep = full ? (cc < Vn)
                             : (fmap(scores[rr * 2048 + cc]) >= thr_u);
            unsigned long long bm = __ballot(keep);
            if (lane == 0) {
                size_t w = ((size_t)h * S + qrow) * 64 + (base >> 5);
                Mask[w]     = (unsigned)bm;
                Mask[w + 1] = (unsigned)(bm >> 32);
            }
        }
        __syncthreads();
    }
}

// ---------------------------------------------------------------------------
// Masked flash attention: per (head, 16-row q tile) block; 32-col chunks.
// Mask bits already encode causal + top-k. Writes attn out [s][h*128+d] fp32.
// ---------------------------------------------------------------------------
__global__ __launch_bounds__(256) void attn_kernel(const float* __restrict__ QR,
                                                   const float* __restrict__ KR,
                                                   const float* __restrict__ V,
                                                   const unsigned* __restrict__ Mask,
                                                   float* __restrict__ Out)
{
    __shared__ float q_lds[16 * 132];
    __shared__ float k_lds[32 * 132];
    __shared__ float v_lds[32 * 132];
    __shared__ float s_lds[16 * 33];
    __shared__ float m_lds[16], l_lds[16], a_lds[16];
    __shared__ unsigned mrow[16];

    const int q0 = blockIdx.x * 16;
    const int h  = blockIdx.y;
    const int tid = threadIdx.x;
    const int r  = tid >> 4;      // 0..15 : q row within tile
    const int ci = tid & 15;      // 0..15 : col group / d group

#pragma unroll
    for (int i = 0; i < 2; i++) {
        int f4 = tid + 256 * i;
        int row = f4 >> 5, c4 = (f4 & 31) * 4;
        *(float4*)&q_lds[row * 132 + c4] =
            *(const float4*)&QR[(size_t)(q0 + row) * E + h * HD + c4];
    }
    if (tid < 16) { m_lds[tid] = NEGF; l_lds[tid] = 0.f; }
    float acc[8] = {0, 0, 0, 0, 0, 0, 0, 0};
    const int kend = q0 + 16;
    __syncthreads();

    for (int cb = 0; cb < kend; cb += 32) {
#pragma unroll
        for (int i = 0; i < 4; i++) {
            int f4 = tid + 256 * i;
            int row = f4 >> 5, c4 = (f4 & 31) * 4;
            *(float4*)&k_lds[row * 132 + c4] =
                *(const float4*)&KR[(size_t)(cb + row) * E + h * HD + c4];
            *(float4*)&v_lds[row * 132 + c4] =
                *(const float4*)&V[(size_t)(cb + row) * E + h * HD + c4];
        }
        if (tid < 16) mrow[tid] = Mask[((size_t)h * S + q0 + tid) * 64 + (cb >> 5)];
        __syncthreads();

        // scores for cols ci, ci+16 of row r
#pragma unroll
        for (int t = 0; t < 2; t++) {
            int j = ci + 16 * t;
            const float* kp = &k_lds[j * 132];
            const float* qp = &q_lds[r * 132];
            float sacc = 0.f;
#pragma unroll 4
            for (int d = 0; d < 128; d += 4) {
                float4 qv = *(const float4*)(qp + d);
                float4 kv = *(const float4*)(kp + d);
                sacc += qv.x * kv.x + qv.y * kv.y + qv.z * kv.z + qv.w * kv.w;
            }
            bool keep = (mrow[r] >> j) & 1u;
            s_lds[r * 33 + j] = keep ? sacc * 0.08838834764831845f : NEGF;
        }
        __syncthreads();

        if (tid < 16) {
            float cmax = NEGF;
            for (int j = 0; j < 32; j++) cmax = fmaxf(cmax, s_lds[tid * 33 + j]);
            float mold = m_lds[tid];
            float mnew = fmaxf(mold, cmax);
            a_lds[tid] = expf(mold - mnew);   // 1.0 when both NEGF
            m_lds[tid] = mnew;
        }
        __syncthreads();

#pragma unroll
        for (int t = 0; t < 2; t++) {
            int j = ci + 16 * t;
            float sv = s_lds[r * 33 + j];
            s_lds[r * 33 + j] = (sv > -1e37f) ? expf(sv - m_lds[r]) : 0.f;
        }
        __syncthreads();

        if (tid < 16) {
            float ps = 0.f;
            for (int j = 0; j < 32; j++) ps += s_lds[tid * 33 + j];
            l_lds[tid] = l_lds[tid] * a_lds[tid] + ps;
        }
        float alpha = a_lds[r];
#pragma unroll
        for (int jj = 0; jj < 8; jj++) acc[jj] *= alpha;
#pragma unroll 4
        for (int c = 0; c < 32; c++) {
            float p = s_lds[r * 33 + c];
            const float* vp = &v_lds[c * 132 + ci * 8];
#pragma unroll
            for (int jj = 0; jj < 8; jj++) acc[jj] += p * vp[jj];
        }
        __syncthreads();
    }

    float invl = 1.0f / l_lds[r];
    float4 o0 = make_float4(acc[0] * invl, acc[1] * invl, acc[2] * invl, acc[3] * invl);
    float4 o1 = make_float4(acc[4] * invl, acc[5] * invl, acc[6] * invl, acc[7] * invl);
    size_t ob = (size_t)(q0 + r) * E + h * HD + ci * 8;
    *(float4*)&Out[ob]     = o0;
    *(float4*)&Out[ob + 4] = o1;
}

// ---------------------------------------------------------------------------
extern "C" void kernel_launch(void* const* d_in, const int* in_sizes, int n_in,
                              void* d_out, int out_size, void* d_ws, size_t ws_size,
                              hipStream_t stream)
{
    (void)in_sizes; (void)n_in; (void)out_size; (void)ws_size;
    const float* hidden = (const float*)d_in[0];
    const float* Wq = (const float*)d_in[1];
    const float* Wk = (const float*)d_in[2];
    const float* Wv = (const float*)d_in[3];
    const float* Wo = (const float*)d_in[4];

    float* ws = (float*)d_ws;
    const size_t SE = (size_t)S * E;   // 8388608
    float* Qb  = ws;
    float* Kb  = ws + SE;
    float* Vb  = ws + 2 * SE;
    float* QRb = ws + 3 * SE;
    float* KRb = ws + 4 * SE;
    unsigned* Maskb = (unsigned*)(ws + 5 * SE);   // H*S*64 u32 = 16 MB
    float* Attnb = Qb;   // Q dead after select_kernel; reuse for attention out

    dim3 gg(E / 128, S / 128);   // (32,16)
    gemm_fp32<<<gg, 256, 0, stream>>>(hidden, Wq, Qb, S, E, E);
    gemm_fp32<<<gg, 256, 0, stream>>>(hidden, Wk, Kb, S, E, E);
    gemm_fp32<<<gg, 256, 0, stream>>>(hidden, Wv, Vb, S, E, E);

    rope_kernel<<<(S * (E / 2)) / 256, 256, 0, stream>>>(Qb, Kb, QRb, KRb);

    const unsigned sel_lds = (7 * 2048 + 7 * 128) * 4 + 2 * 256 * 4;  // 62976 B
    select_kernel<<<dim3((S + 6) / 7, H), 256, sel_lds, stream>>>(Qb, Kb, Maskb);

    attn_kernel<<<dim3(S / 16, H), 256, 0, stream>>>(QRb, KRb, Vb, Maskb, Attnb);

    gemm_fp32<<<gg, 256, 0, stream>>>(Attnb, Wo, (float*)d_out, S, E, E);
}

// Round 2
// 5262.742 us; speedup vs baseline: 2.0027x; 2.0027x over previous
//
#include <hip/hip_runtime.h>
#include <math.h>

#define S   2048
#define E   4096
#define H   32
#define HD  128
#define NKEEP 205
#define NEGF -3.0e38f

typedef unsigned short ushort_t;
typedef __attribute__((ext_vector_type(8))) __bf16 bf16x8;
typedef __attribute__((ext_vector_type(4))) float f32x4;

__device__ __forceinline__ unsigned fmap(float x) {
    unsigned u = __float_as_uint(x);
    return (u & 0x80000000u) ? ~u : (u | 0x80000000u);
}

__device__ __forceinline__ ushort_t f2bf(float f) {
    unsigned u = __float_as_uint(f);
    u += 0x7FFFu + ((u >> 16) & 1u);   // RNE; inputs finite
    return (ushort_t)(u >> 16);
}

// ---------------------------------------------------------------------------
// fp32 tiled GEMM (Q/K projections — precision-critical for top-k selection)
// ---------------------------------------------------------------------------
__global__ __launch_bounds__(256) void gemm_fp32(const float* __restrict__ A,
                                                 const float* __restrict__ B,
                                                 float* __restrict__ C,
                                                 int M, int N, int Kd)
{
    __shared__ float As[8][132];
    __shared__ float Bs[8][132];
    const int tid = threadIdx.x;
    const int tx = tid & 15, ty = tid >> 4;
    const int bm = blockIdx.y, bn = blockIdx.x;
    const int arow = tid >> 1, ac4 = (tid & 1) * 4;
    const int brow = tid >> 5, bc4 = (tid & 31) * 4;
    const float* Ap = A + (size_t)(bm * 128 + arow) * Kd + ac4;
    const float* Bp = B + (size_t)brow * N + bn * 128 + bc4;

    float acc[8][8];
#pragma unroll
    for (int i = 0; i < 8; i++)
#pragma unroll
        for (int j = 0; j < 8; j++) acc[i][j] = 0.f;

    for (int k0 = 0; k0 < Kd; k0 += 8) {
        float4 av = *(const float4*)(Ap + k0);
        float4 bv = *(const float4*)(Bp + (size_t)k0 * N);
        __syncthreads();
        As[ac4 + 0][arow] = av.x;
        As[ac4 + 1][arow] = av.y;
        As[ac4 + 2][arow] = av.z;
        As[ac4 + 3][arow] = av.w;
        *(float4*)&Bs[brow][bc4] = bv;
        __syncthreads();
#pragma unroll
        for (int kk = 0; kk < 8; kk++) {
            float a[8], b[8];
            *(float4*)&a[0] = *(const float4*)&As[kk][ty * 8];
            *(float4*)&a[4] = *(const float4*)&As[kk][ty * 8 + 4];
            *(float4*)&b[0] = *(const float4*)&Bs[kk][tx * 8];
            *(float4*)&b[4] = *(const float4*)&Bs[kk][tx * 8 + 4];
#pragma unroll
            for (int i = 0; i < 8; i++)
#pragma unroll
                for (int j = 0; j < 8; j++)
                    acc[i][j] += a[i] * b[j];
        }
    }
    const size_t row0 = bm * 128 + ty * 8;
    const size_t col0 = bn * 128 + tx * 8;
#pragma unroll
    for (int i = 0; i < 8; i++) {
        *(float4*)&C[(row0 + i) * N + col0]     = make_float4(acc[i][0], acc[i][1], acc[i][2], acc[i][3]);
        *(float4*)&C[(row0 + i) * N + col0 + 4] = make_float4(acc[i][4], acc[i][5], acc[i][6], acc[i][7]);
    }
}

// ---------------------------------------------------------------------------
// fp32 -> bf16 elementwise convert (8 elems/thread)
// ---------------------------------------------------------------------------
__global__ __launch_bounds__(256) void cvt_bf16(const float* __restrict__ in,
                                                ushort_t* __restrict__ out)
{
    size_t i8 = ((size_t)blockIdx.x * 256 + threadIdx.x) * 8;
    float4 a = *(const float4*)&in[i8];
    float4 b = *(const float4*)&in[i8 + 4];
    ushort_t r[8] = { f2bf(a.x), f2bf(a.y), f2bf(a.z), f2bf(a.w),
                      f2bf(b.x), f2bf(b.y), f2bf(b.z), f2bf(b.w) };
    *(uint4*)&out[i8] = *(uint4*)r;
}

// ---------------------------------------------------------------------------
// W fp32 [K][N] row-major -> bf16 W^T [N][K] (32x32 LDS tile transpose)
// ---------------------------------------------------------------------------
__global__ __launch_bounds__(256) void transp_cvt(const float* __restrict__ W,
                                                  ushort_t* __restrict__ Wt)
{
    __shared__ ushort_t tile[32][34];
    const int tid = threadIdx.x;
    const int k0 = blockIdx.y * 32, n0 = blockIdx.x * 32;
    const int row = tid >> 3, c4 = (tid & 7) * 4;
    float4 v = *(const float4*)&W[(size_t)(k0 + row) * E + n0 + c4];
    tile[row][c4 + 0] = f2bf(v.x);
    tile[row][c4 + 1] = f2bf(v.y);
    tile[row][c4 + 2] = f2bf(v.z);
    tile[row][c4 + 3] = f2bf(v.w);
    __syncthreads();
    ushort_t o[4] = { tile[c4 + 0][row], tile[c4 + 1][row],
                      tile[c4 + 2][row], tile[c4 + 3][row] };
    *(ushort2*)&o[0];  // no-op; keep o in regs
    *((uint2*)&Wt[(size_t)(n0 + row) * E + k0 + c4]) = *(uint2*)o;
}

// ---------------------------------------------------------------------------
// bf16 MFMA GEMM: C fp32[M][N] = A_bf16[M][K] x Bt_bf16[N][K].
// 128x128 tile, BK=32, 4 waves in 2x2, 4x4 frags of 16x16x32 each.
// ---------------------------------------------------------------------------
__global__ __launch_bounds__(256) void gemm_bf16t(const ushort_t* __restrict__ A,
                                                  const ushort_t* __restrict__ Bt,
                                                  float* __restrict__ C,
                                                  int M, int N, int Kd)
{
    __shared__ ushort_t As[128 * 40];   // pad 40 bf16: conflict-free b128 frag reads
    __shared__ ushort_t Bs[128 * 40];
    const int tid = threadIdx.x;
    const int m0 = blockIdx.y * 128, n0 = blockIdx.x * 128;
    const int lane = tid & 63, w = tid >> 6;
    const int wm = (w & 1) * 64, wn = (w >> 1) * 64;
    const int ll = lane & 15, lh = lane >> 4;
    const int srow = tid >> 2, sk = (tid & 3) * 8;

    f32x4 acc[4][4];
#pragma unroll
    for (int i = 0; i < 4; i++)
#pragma unroll
        for (int j = 0; j < 4; j++) acc[i][j] = f32x4{0.f, 0.f, 0.f, 0.f};

    const ushort_t* Ap = A + (size_t)(m0 + srow) * Kd + sk;
    const ushort_t* Bp = Bt + (size_t)(n0 + srow) * Kd + sk;

    for (int k0 = 0; k0 < Kd; k0 += 32) {
        uint4 av0 = *(const uint4*)(Ap + k0);
        uint4 av1 = *(const uint4*)(Ap + k0 + (size_t)64 * Kd);
        uint4 bv0 = *(const uint4*)(Bp + k0);
        uint4 bv1 = *(const uint4*)(Bp + k0 + (size_t)64 * Kd);
        __syncthreads();
        *(uint4*)&As[srow * 40 + sk]        = av0;
        *(uint4*)&As[(srow + 64) * 40 + sk] = av1;
        *(uint4*)&Bs[srow * 40 + sk]        = bv0;
        *(uint4*)&Bs[(srow + 64) * 40 + sk] = bv1;
        __syncthreads();

        bf16x8 af[4], bfr[4];
#pragma unroll
        for (int i = 0; i < 4; i++)
            af[i] = *(const bf16x8*)&As[(wm + 16 * i + ll) * 40 + lh * 8];
#pragma unroll
        for (int j = 0; j < 4; j++)
            bfr[j] = *(const bf16x8*)&Bs[(wn + 16 * j + ll) * 40 + lh * 8];
#pragma unroll
        for (int i = 0; i < 4; i++)
#pragma unroll
            for (int j = 0; j < 4; j++)
                acc[i][j] = __builtin_amdgcn_mfma_f32_16x16x32_bf16(af[i], bfr[j], acc[i][j], 0, 0, 0);
    }
    // C/D layout: col = lane&15, row = (lane>>4)*4 + reg  [m89-verified]
#pragma unroll
    for (int i = 0; i < 4; i++)
#pragma unroll
        for (int j = 0; j < 4; j++)
#pragma unroll
            for (int r = 0; r < 4; r++)
                C[(size_t)(m0 + wm + 16 * i + lh * 4 + r) * N + (n0 + wn + 16 * j + ll)] = acc[i][j][r];
}

// ---------------------------------------------------------------------------
// RoPE (in-place): one thread per (s,h,d<64)
// ---------------------------------------------------------------------------
__global__ __launch_bounds__(256) void rope_kernel(float* __restrict__ Q,
                                                   float* __restrict__ K)
{
    int idx = blockIdx.x * 256 + threadIdx.x;
    int s   = idx >> 11;
    int rem = idx & 2047;
    int h   = rem >> 6;
    int d   = rem & 63;
    float inv = exp2f(-0.20762050593046f * (float)d);  // 10000^(-d/64)
    float ang = (float)s * inv;
    float sn, cs;
    sincosf(ang, &sn, &cs);
    size_t base = (size_t)s * E + h * HD;
    float q0 = Q[base + d], q1 = Q[base + d + 64];
    Q[base + d]      = q0 * cs - q1 * sn;
    Q[base + d + 64] = q1 * cs + q0 * sn;
    float k0 = K[base + d], k1 = K[base + d + 64];
    K[base + d]      = k0 * cs - k1 * sn;
    K[base + d + 64] = k1 * cs + k0 * sn;
}

// ---------------------------------------------------------------------------
// Selection v2: block = 4 query rows x 1 head; ONE WAVE PER ROW.
// Phase 1: draft scores via LDS-staged K chunks (64 cols), stored fmap'd u32.
// Phase 2: wave-private exact radix select (no block barriers), mask via ballot.
// LDS: qs 2.1K + ks 33.8K + sc 32K + hist 4K = 72KB -> 2 blocks/CU.
// ---------------------------------------------------------------------------
__global__ __launch_bounds__(256) void select_kernel(const float* __restrict__ Q,
                                                     const float* __restrict__ K,
                                                     unsigned* __restrict__ Mask)
{
    __shared__ float qs[4][132];
    __shared__ float ks[64][132];
    __shared__ unsigned sc[4][2048];
    __shared__ unsigned hist[4][256];

    const int tid  = threadIdx.x;
    const int q0   = blockIdx.x * 4;
    const int h    = blockIdx.y;
    const int w    = tid >> 6, lane = tid & 63;
    const int qrow = q0 + w;

    if (tid < 128) {
        int row = tid >> 5, c4 = (tid & 31) * 4;
        *(float4*)&qs[row][c4] = *(const float4*)&Q[(size_t)(q0 + row) * E + h * HD + c4];
    }
    {   // zero sc (cols beyond last chunk must read as 0 = masked)
        uint4* scv = (uint4*)sc;
        uint4 z = make_uint4(0u, 0u, 0u, 0u);
        for (int i = tid; i < 2048; i += 256) scv[i] = z;
    }
    __syncthreads();

    const int nch = (q0 + 4 + 63) >> 6;
    for (int ch = 0; ch < nch; ch++) {
        const int cb = ch << 6;
#pragma unroll
        for (int i = 0; i < 8; i++) {
            int idx = tid + (i << 8);
            int row = idx >> 5, d0 = (idx & 31) * 4;
            *(float4*)&ks[row][d0] =
                *(const float4*)&K[(size_t)(cb + row) * E + h * HD + d0];
        }
        __syncthreads();
        const int col = cb + lane;
        const float* kp = ks[lane];
        const float* qp = qs[w];
        float acc = 0.f;
#pragma unroll 8
        for (int d = 0; d < 128; d += 4) {
            float4 kv = *(const float4*)(kp + d);
            float4 qv = *(const float4*)(qp + d);
            acc += kv.x * qv.x + kv.y * qv.y + kv.z * qv.z + kv.w * qv.w;
        }
        sc[w][col] = (col <= qrow) ? fmap(acc) : 0u;
        __syncthreads();
    }

    // ---- wave-private exact radix select (205th largest) ----
    const int Vn = qrow + 1;
    unsigned thr = 1u;                 // full-keep case: any real score (fmap>0)
    if (Vn > NKEEP) {
        unsigned p = 0u, need = NKEEP;
        for (int pass = 0; pass < 4; pass++) {
            const int shift = 24 - 8 * pass;
            *(uint4*)&hist[w][lane * 4] = make_uint4(0u, 0u, 0u, 0u);
            __threadfence_block();
            for (int i = 0; i < 32; i++) {
                unsigned v = sc[w][lane + (i << 6)];
                bool part = (pass == 0) ? true : ((v >> (shift + 8)) == p);
                if (part) atomicAdd(&hist[w][(v >> shift) & 255u], 1u);
            }
            __threadfence_block();
            uint4 hv = *(const uint4*)&hist[w][lane * 4];
            unsigned t3 = hv.w;
            unsigned t2 = t3 + hv.z;
            unsigned t1 = t2 + hv.y;
            unsigned t0 = t1 + hv.x;
            unsigned s  = t0;
            unsigned run = s;
#pragma unroll
            for (int off = 1; off < 64; off <<= 1) {
                unsigned o = __shfl_down(run, off);
                if (lane + off < 64) run += o;
            }
            const unsigned nxt = run - s;     // suffix over lanes > this one
            unsigned tj[4] = { t0, t1, t2, t3 };
            bool m = false; unsigned nb = 0u, nn = 0u;
#pragma unroll
            for (int j = 0; j < 4; j++) {
                unsigned sb  = nxt + tj[j];
                unsigned sb1 = nxt + ((j < 3) ? tj[j + 1] : 0u);
                if (!m && need <= sb && need > sb1) {
                    m = true; nb = (unsigned)(lane * 4 + j); nn = need - sb1;
                }
            }
            unsigned long long bal = __ballot(m);
            int src = __ffsll(bal) - 1;
            p    = (p << 8) | __shfl(nb, src);
            need = __shfl(nn, src);
        }
        thr = p;
    }

    // ---- mask write: 64-bit ballot per 64 cols ----
    const size_t mbase = ((size_t)h * S + qrow) * 64;
    for (int base = 0; base < S; base += 64) {
        bool keep = sc[w][base + lane] >= thr;
        unsigned long long bm = __ballot(keep);
        if (lane == 0) {
            Mask[mbase + (base >> 5)]     = (unsigned)bm;
            Mask[mbase + (base >> 5) + 1] = (unsigned)(bm >> 32);
        }
    }
}

// ---------------------------------------------------------------------------
// Masked flash attention (unchanged from R1)
// ---------------------------------------------------------------------------
__global__ __launch_bounds__(256) void attn_kernel(const float* __restrict__ QR,
                                                   const float* __restrict__ KR,
                                                   const float* __restrict__ V,
                                                   const unsigned* __restrict__ Mask,
                                                   float* __restrict__ Out)
{
    __shared__ float q_lds[16 * 132];
    __shared__ float k_lds[32 * 132];
    __shared__ float v_lds[32 * 132];
    __shared__ float s_lds[16 * 33];
    __shared__ float m_lds[16], l_lds[16], a_lds[16];
    __shared__ unsigned mrow[16];

    const int q0 = blockIdx.x * 16;
    const int h  = blockIdx.y;
    const int tid = threadIdx.x;
    const int r  = tid >> 4;
    const int ci = tid & 15;

#pragma unroll
    for (int i = 0; i < 2; i++) {
        int f4 = tid + 256 * i;
        int row = f4 >> 5, c4 = (f4 & 31) * 4;
        *(float4*)&q_lds[row * 132 + c4] =
            *(const float4*)&QR[(size_t)(q0 + row) * E + h * HD + c4];
    }
    if (tid < 16) { m_lds[tid] = NEGF; l_lds[tid] = 0.f; }
    float acc[8] = {0, 0, 0, 0, 0, 0, 0, 0};
    const int kend = q0 + 16;
    __syncthreads();

    for (int cb = 0; cb < kend; cb += 32) {
#pragma unroll
        for (int i = 0; i < 4; i++) {
            int f4 = tid + 256 * i;
            int row = f4 >> 5, c4 = (f4 & 31) * 4;
            *(float4*)&k_lds[row * 132 + c4] =
                *(const float4*)&KR[(size_t)(cb + row) * E + h * HD + c4];
            *(float4*)&v_lds[row * 132 + c4] =
                *(const float4*)&V[(size_t)(cb + row) * E + h * HD + c4];
        }
        if (tid < 16) mrow[tid] = Mask[((size_t)h * S + q0 + tid) * 64 + (cb >> 5)];
        __syncthreads();

#pragma unroll
        for (int t = 0; t < 2; t++) {
            int j = ci + 16 * t;
            const float* kp = &k_lds[j * 132];
            const float* qp = &q_lds[r * 132];
            float sacc = 0.f;
#pragma unroll 4
            for (int d = 0; d < 128; d += 4) {
                float4 qv = *(const float4*)(qp + d);
                float4 kv = *(const float4*)(kp + d);
                sacc += qv.x * kv.x + qv.y * kv.y + qv.z * kv.z + qv.w * kv.w;
            }
            bool keep = (mrow[r] >> j) & 1u;
            s_lds[r * 33 + j] = keep ? sacc * 0.08838834764831845f : NEGF;
        }
        __syncthreads();

        if (tid < 16) {
            float cmax = NEGF;
            for (int j = 0; j < 32; j++) cmax = fmaxf(cmax, s_lds[tid * 33 + j]);
            float mold = m_lds[tid];
            float mnew = fmaxf(mold, cmax);
            a_lds[tid] = expf(mold - mnew);
            m_lds[tid] = mnew;
        }
        __syncthreads();

#pragma unroll
        for (int t = 0; t < 2; t++) {
            int j = ci + 16 * t;
            float sv = s_lds[r * 33 + j];
            s_lds[r * 33 + j] = (sv > -1e37f) ? expf(sv - m_lds[r]) : 0.f;
        }
        __syncthreads();

        if (tid < 16) {
            float ps = 0.f;
            for (int j = 0; j < 32; j++) ps += s_lds[tid * 33 + j];
            l_lds[tid] = l_lds[tid] * a_lds[tid] + ps;
        }
        float alpha = a_lds[r];
#pragma unroll
        for (int jj = 0; jj < 8; jj++) acc[jj] *= alpha;
#pragma unroll 4
        for (int c = 0; c < 32; c++) {
            float p = s_lds[r * 33 + c];
            const float* vp = &v_lds[c * 132 + ci * 8];
#pragma unroll
            for (int jj = 0; jj < 8; jj++) acc[jj] += p * vp[jj];
        }
        __syncthreads();
    }

    float invl = 1.0f / l_lds[r];
    float4 o0 = make_float4(acc[0] * invl, acc[1] * invl, acc[2] * invl, acc[3] * invl);
    float4 o1 = make_float4(acc[4] * invl, acc[5] * invl, acc[6] * invl, acc[7] * invl);
    size_t ob = (size_t)(q0 + r) * E + h * HD + ci * 8;
    *(float4*)&Out[ob]     = o0;
    *(float4*)&Out[ob + 4] = o1;
}

// ---------------------------------------------------------------------------
extern "C" void kernel_launch(void* const* d_in, const int* in_sizes, int n_in,
                              void* d_out, int out_size, void* d_ws, size_t ws_size,
                              hipStream_t stream)
{
    (void)in_sizes; (void)n_in; (void)out_size; (void)ws_size;
    const float* hidden = (const float*)d_in[0];
    const float* Wq = (const float*)d_in[1];
    const float* Wk = (const float*)d_in[2];
    const float* Wv = (const float*)d_in[3];
    const float* Wo = (const float*)d_in[4];

    float* ws = (float*)d_ws;
    const size_t SE = (size_t)S * E;               // 8388608
    float*    Qb    = ws;                          // [0,   SE)
    float*    Kb    = ws + SE;                     // [SE,  2SE)
    float*    Vb    = ws + 2 * SE;                 // [2SE, 3SE)
    float*    AttnF = ws + 3 * SE;                 // [3SE, 4SE)  (shared with Wt)
    ushort_t* Wt    = (ushort_t*)(ws + 3 * SE);    //   same slot: E*E bf16 = SE floats
    unsigned* Maskb = (unsigned*)(ws + 4 * SE);    // [4SE, 4.5SE): H*S*64 u32
    ushort_t* Hbf   = (ushort_t*)(ws + 4 * SE + SE / 2);  // [4.5SE, 5SE): SE bf16
    // total = 5*SE floats = 168 MB

    dim3 gg(E / 128, S / 128);   // (32,16)

    gemm_fp32<<<gg, 256, 0, stream>>>(hidden, Wq, Qb, S, E, E);
    gemm_fp32<<<gg, 256, 0, stream>>>(hidden, Wk, Kb, S, E, E);

    cvt_bf16<<<SE / 2048, 256, 0, stream>>>(hidden, Hbf);
    transp_cvt<<<dim3(E / 32, E / 32), 256, 0, stream>>>(Wv, Wt);
    gemm_bf16t<<<gg, 256, 0, stream>>>(Hbf, Wt, Vb, S, E, E);

    select_kernel<<<dim3(S / 4, H), 256, 0, stream>>>(Qb, Kb, Maskb);

    rope_kernel<<<(S * 2048) / 256, 256, 0, stream>>>(Qb, Kb);

    attn_kernel<<<dim3(S / 16, H), 256, 0, stream>>>(Qb, Kb, Vb, Maskb, AttnF);

    cvt_bf16<<<SE / 2048, 256, 0, stream>>>(AttnF, Hbf);
    transp_cvt<<<dim3(E / 32, E / 32), 256, 0, stream>>>(Wo, Wt);
    gemm_bf16t<<<gg, 256, 0, stream>>>(Hbf, Wt, (float*)d_out, S, E, E);
}

// Round 3
// 4103.608 us; speedup vs baseline: 2.5685x; 1.2825x over previous
//
#include <hip/hip_runtime.h>
#include <math.h>

#define S   2048
#define E   4096
#define H   32
#define HD  128
#define NKEEP 205
#define NEGF -3.0e38f

typedef unsigned short ushort_t;
typedef __attribute__((ext_vector_type(8))) __bf16 bf16x8;
typedef __attribute__((ext_vector_type(4))) float f32x4;

__device__ __forceinline__ unsigned fmap(float x) {
    unsigned u = __float_as_uint(x);
    return (u & 0x80000000u) ? ~u : (u | 0x80000000u);
}

__device__ __forceinline__ ushort_t f2bf(float f) {
    unsigned u = __float_as_uint(f);
    u += 0x7FFFu + ((u >> 16) & 1u);   // RNE; inputs finite
    return (ushort_t)(u >> 16);
}

// ---------------------------------------------------------------------------
// fp32 tiled GEMM (Q/K projections — precision-critical for top-k selection)
// ---------------------------------------------------------------------------
__global__ __launch_bounds__(256) void gemm_fp32(const float* __restrict__ A,
                                                 const float* __restrict__ B,
                                                 float* __restrict__ C,
                                                 int M, int N, int Kd)
{
    __shared__ float As[8][132];
    __shared__ float Bs[8][132];
    const int tid = threadIdx.x;
    const int tx = tid & 15, ty = tid >> 4;
    const int bm = blockIdx.y, bn = blockIdx.x;
    const int arow = tid >> 1, ac4 = (tid & 1) * 4;
    const int brow = tid >> 5, bc4 = (tid & 31) * 4;
    const float* Ap = A + (size_t)(bm * 128 + arow) * Kd + ac4;
    const float* Bp = B + (size_t)brow * N + bn * 128 + bc4;

    float acc[8][8];
#pragma unroll
    for (int i = 0; i < 8; i++)
#pragma unroll
        for (int j = 0; j < 8; j++) acc[i][j] = 0.f;

    for (int k0 = 0; k0 < Kd; k0 += 8) {
        float4 av = *(const float4*)(Ap + k0);
        float4 bv = *(const float4*)(Bp + (size_t)k0 * N);
        __syncthreads();
        As[ac4 + 0][arow] = av.x;
        As[ac4 + 1][arow] = av.y;
        As[ac4 + 2][arow] = av.z;
        As[ac4 + 3][arow] = av.w;
        *(float4*)&Bs[brow][bc4] = bv;
        __syncthreads();
#pragma unroll
        for (int kk = 0; kk < 8; kk++) {
            float a[8], b[8];
            *(float4*)&a[0] = *(const float4*)&As[kk][ty * 8];
            *(float4*)&a[4] = *(const float4*)&As[kk][ty * 8 + 4];
            *(float4*)&b[0] = *(const float4*)&Bs[kk][tx * 8];
            *(float4*)&b[4] = *(const float4*)&Bs[kk][tx * 8 + 4];
#pragma unroll
            for (int i = 0; i < 8; i++)
#pragma unroll
                for (int j = 0; j < 8; j++)
                    acc[i][j] += a[i] * b[j];
        }
    }
    const size_t row0 = bm * 128 + ty * 8;
    const size_t col0 = bn * 128 + tx * 8;
#pragma unroll
    for (int i = 0; i < 8; i++) {
        *(float4*)&C[(row0 + i) * N + col0]     = make_float4(acc[i][0], acc[i][1], acc[i][2], acc[i][3]);
        *(float4*)&C[(row0 + i) * N + col0 + 4] = make_float4(acc[i][4], acc[i][5], acc[i][6], acc[i][7]);
    }
}

// ---------------------------------------------------------------------------
// fp32 -> bf16 elementwise convert (8 elems/thread)
// ---------------------------------------------------------------------------
__global__ __launch_bounds__(256) void cvt_bf16(const float* __restrict__ in,
                                                ushort_t* __restrict__ out)
{
    size_t i8 = ((size_t)blockIdx.x * 256 + threadIdx.x) * 8;
    float4 a = *(const float4*)&in[i8];
    float4 b = *(const float4*)&in[i8 + 4];
    ushort_t r[8] = { f2bf(a.x), f2bf(a.y), f2bf(a.z), f2bf(a.w),
                      f2bf(b.x), f2bf(b.y), f2bf(b.z), f2bf(b.w) };
    *(uint4*)&out[i8] = *(uint4*)r;
}

// ---------------------------------------------------------------------------
// W fp32 [K][N] row-major -> bf16 W^T [N][K] (32x32 LDS tile transpose)
// ---------------------------------------------------------------------------
__global__ __launch_bounds__(256) void transp_cvt(const float* __restrict__ W,
                                                  ushort_t* __restrict__ Wt)
{
    __shared__ ushort_t tile[32][34];
    const int tid = threadIdx.x;
    const int k0 = blockIdx.y * 32, n0 = blockIdx.x * 32;
    const int row = tid >> 3, c4 = (tid & 7) * 4;
    float4 v = *(const float4*)&W[(size_t)(k0 + row) * E + n0 + c4];
    tile[row][c4 + 0] = f2bf(v.x);
    tile[row][c4 + 1] = f2bf(v.y);
    tile[row][c4 + 2] = f2bf(v.z);
    tile[row][c4 + 3] = f2bf(v.w);
    __syncthreads();
    ushort_t o[4] = { tile[c4 + 0][row], tile[c4 + 1][row],
                      tile[c4 + 2][row], tile[c4 + 3][row] };
    *((uint2*)&Wt[(size_t)(n0 + row) * E + k0 + c4]) = *(uint2*)o;
}

// ---------------------------------------------------------------------------
// V fp32 [s][h*128+d] -> bf16 V^T [h][d][s]  (32x32 tile transpose)
// ---------------------------------------------------------------------------
__global__ __launch_bounds__(256) void vtransp(const float* __restrict__ V,
                                               ushort_t* __restrict__ Vt)
{
    __shared__ ushort_t tile[32][33];
    const int tid = threadIdx.x;
    const int s0 = blockIdx.y * 32, e0 = blockIdx.x * 32;
    const int row = tid >> 3, c4 = (tid & 7) * 4;
    float4 v = *(const float4*)&V[(size_t)(s0 + row) * E + e0 + c4];
    tile[row][c4 + 0] = f2bf(v.x);
    tile[row][c4 + 1] = f2bf(v.y);
    tile[row][c4 + 2] = f2bf(v.z);
    tile[row][c4 + 3] = f2bf(v.w);
    __syncthreads();
    const int hh = e0 >> 7, d = (e0 & 127) + row;
    ushort_t o[4] = { tile[c4 + 0][row], tile[c4 + 1][row],
                      tile[c4 + 2][row], tile[c4 + 3][row] };
    *((uint2*)&Vt[((size_t)(hh * HD + d)) * S + s0 + c4]) = *(uint2*)o;
}

// ---------------------------------------------------------------------------
// bf16 MFMA GEMM: C fp32[M][N] = A_bf16[M][K] x Bt_bf16[N][K].
// ---------------------------------------------------------------------------
__global__ __launch_bounds__(256) void gemm_bf16t(const ushort_t* __restrict__ A,
                                                  const ushort_t* __restrict__ Bt,
                                                  float* __restrict__ C,
                                                  int M, int N, int Kd)
{
    __shared__ ushort_t As[128 * 40];
    __shared__ ushort_t Bs[128 * 40];
    const int tid = threadIdx.x;
    const int m0 = blockIdx.y * 128, n0 = blockIdx.x * 128;
    const int lane = tid & 63, w = tid >> 6;
    const int wm = (w & 1) * 64, wn = (w >> 1) * 64;
    const int ll = lane & 15, lh = lane >> 4;
    const int srow = tid >> 2, sk = (tid & 3) * 8;

    f32x4 acc[4][4];
#pragma unroll
    for (int i = 0; i < 4; i++)
#pragma unroll
        for (int j = 0; j < 4; j++) acc[i][j] = f32x4{0.f, 0.f, 0.f, 0.f};

    const ushort_t* Ap = A + (size_t)(m0 + srow) * Kd + sk;
    const ushort_t* Bp = Bt + (size_t)(n0 + srow) * Kd + sk;

    for (int k0 = 0; k0 < Kd; k0 += 32) {
        uint4 av0 = *(const uint4*)(Ap + k0);
        uint4 av1 = *(const uint4*)(Ap + k0 + (size_t)64 * Kd);
        uint4 bv0 = *(const uint4*)(Bp + k0);
        uint4 bv1 = *(const uint4*)(Bp + k0 + (size_t)64 * Kd);
        __syncthreads();
        *(uint4*)&As[srow * 40 + sk]        = av0;
        *(uint4*)&As[(srow + 64) * 40 + sk] = av1;
        *(uint4*)&Bs[srow * 40 + sk]        = bv0;
        *(uint4*)&Bs[(srow + 64) * 40 + sk] = bv1;
        __syncthreads();

        bf16x8 af[4], bfr[4];
#pragma unroll
        for (int i = 0; i < 4; i++)
            af[i] = *(const bf16x8*)&As[(wm + 16 * i + ll) * 40 + lh * 8];
#pragma unroll
        for (int j = 0; j < 4; j++)
            bfr[j] = *(const bf16x8*)&Bs[(wn + 16 * j + ll) * 40 + lh * 8];
#pragma unroll
        for (int i = 0; i < 4; i++)
#pragma unroll
            for (int j = 0; j < 4; j++)
                acc[i][j] = __builtin_amdgcn_mfma_f32_16x16x32_bf16(af[i], bfr[j], acc[i][j], 0, 0, 0);
    }
#pragma unroll
    for (int i = 0; i < 4; i++)
#pragma unroll
        for (int j = 0; j < 4; j++)
#pragma unroll
            for (int r = 0; r < 4; r++)
                C[(size_t)(m0 + wm + 16 * i + lh * 4 + r) * N + (n0 + wn + 16 * j + ll)] = acc[i][j][r];
}

// ---------------------------------------------------------------------------
// RoPE: fp32 Q/K in, bf16 QR/KR out.
// ---------------------------------------------------------------------------
__global__ __launch_bounds__(256) void rope_bf16(const float* __restrict__ Q,
                                                 const float* __restrict__ K,
                                                 ushort_t* __restrict__ QR,
                                                 ushort_t* __restrict__ KR)
{
    int idx = blockIdx.x * 256 + threadIdx.x;
    int s   = idx >> 11;
    int rem = idx & 2047;
    int h   = rem >> 6;
    int d   = rem & 63;
    float inv = exp2f(-0.20762050593046f * (float)d);  // 10000^(-d/64)
    float ang = (float)s * inv;
    float sn, cs;
    sincosf(ang, &sn, &cs);
    size_t base = (size_t)s * E + h * HD;
    float q0 = Q[base + d], q1 = Q[base + d + 64];
    QR[base + d]      = f2bf(q0 * cs - q1 * sn);
    QR[base + d + 64] = f2bf(q1 * cs + q0 * sn);
    float k0 = K[base + d], k1 = K[base + d + 64];
    KR[base + d]      = f2bf(k0 * cs - k1 * sn);
    KR[base + d + 64] = f2bf(k1 * cs + k0 * sn);
}

// ---------------------------------------------------------------------------
// Selection (unchanged from R2): wave-private exact radix select per q-row.
// ---------------------------------------------------------------------------
__global__ __launch_bounds__(256) void select_kernel(const float* __restrict__ Q,
                                                     const float* __restrict__ K,
                                                     unsigned* __restrict__ Mask)
{
    __shared__ float qs[4][132];
    __shared__ float ks[64][132];
    __shared__ unsigned sc[4][2048];
    __shared__ unsigned hist[4][256];

    const int tid  = threadIdx.x;
    const int q0   = blockIdx.x * 4;
    const int h    = blockIdx.y;
    const int w    = tid >> 6, lane = tid & 63;
    const int qrow = q0 + w;

    if (tid < 128) {
        int row = tid >> 5, c4 = (tid & 31) * 4;
        *(float4*)&qs[row][c4] = *(const float4*)&Q[(size_t)(q0 + row) * E + h * HD + c4];
    }
    {
        uint4* scv = (uint4*)sc;
        uint4 z = make_uint4(0u, 0u, 0u, 0u);
        for (int i = tid; i < 2048; i += 256) scv[i] = z;
    }
    __syncthreads();

    const int nch = (q0 + 4 + 63) >> 6;
    for (int ch = 0; ch < nch; ch++) {
        const int cb = ch << 6;
#pragma unroll
        for (int i = 0; i < 8; i++) {
            int idx = tid + (i << 8);
            int row = idx >> 5, d0 = (idx & 31) * 4;
            *(float4*)&ks[row][d0] =
                *(const float4*)&K[(size_t)(cb + row) * E + h * HD + d0];
        }
        __syncthreads();
        const int col = cb + lane;
        const float* kp = ks[lane];
        const float* qp = qs[w];
        float acc = 0.f;
#pragma unroll 8
        for (int d = 0; d < 128; d += 4) {
            float4 kv = *(const float4*)(kp + d);
            float4 qv = *(const float4*)(qp + d);
            acc += kv.x * qv.x + kv.y * qv.y + kv.z * qv.z + kv.w * qv.w;
        }
        sc[w][col] = (col <= qrow) ? fmap(acc) : 0u;
        __syncthreads();
    }

    const int Vn = qrow + 1;
    unsigned thr = 1u;
    if (Vn > NKEEP) {
        unsigned p = 0u, need = NKEEP;
        for (int pass = 0; pass < 4; pass++) {
            const int shift = 24 - 8 * pass;
            *(uint4*)&hist[w][lane * 4] = make_uint4(0u, 0u, 0u, 0u);
            __threadfence_block();
            for (int i = 0; i < 32; i++) {
                unsigned v = sc[w][lane + (i << 6)];
                bool part = (pass == 0) ? true : ((v >> (shift + 8)) == p);
                if (part) atomicAdd(&hist[w][(v >> shift) & 255u], 1u);
            }
            __threadfence_block();
            uint4 hv = *(const uint4*)&hist[w][lane * 4];
            unsigned t3 = hv.w;
            unsigned t2 = t3 + hv.z;
            unsigned t1 = t2 + hv.y;
            unsigned t0 = t1 + hv.x;
            unsigned s  = t0;
            unsigned run = s;
#pragma unroll
            for (int off = 1; off < 64; off <<= 1) {
                unsigned o = __shfl_down(run, off);
                if (lane + off < 64) run += o;
            }
            const unsigned nxt = run - s;
            unsigned tj[4] = { t0, t1, t2, t3 };
            bool m = false; unsigned nb = 0u, nn = 0u;
#pragma unroll
            for (int j = 0; j < 4; j++) {
                unsigned sb  = nxt + tj[j];
                unsigned sb1 = nxt + ((j < 3) ? tj[j + 1] : 0u);
                if (!m && need <= sb && need > sb1) {
                    m = true; nb = (unsigned)(lane * 4 + j); nn = need - sb1;
                }
            }
            unsigned long long bal = __ballot(m);
            int src = __ffsll(bal) - 1;
            p    = (p << 8) | __shfl(nb, src);
            need = __shfl(nn, src);
        }
        thr = p;
    }

    const size_t mbase = ((size_t)h * S + qrow) * 64;
    for (int base = 0; base < S; base += 64) {
        bool keep = sc[w][base + lane] >= thr;
        unsigned long long bm = __ballot(keep);
        if (lane == 0) {
            Mask[mbase + (base >> 5)]     = (unsigned)bm;
            Mask[mbase + (base >> 5) + 1] = (unsigned)(bm >> 32);
        }
    }
}

// ---------------------------------------------------------------------------
// MFMA flash attention. Block = (64 q rows) x (1 head); 4 waves, 16 q rows
// each. Per 64-kv chunk: Sc^T = K·Q^T (kv rows, q cols), masked online
// softmax in C-layout (1 shuffle-reduce pair per chunk), P^T fed to PV as
// the B operand via cross-lane shuffles; O^T accumulates in C-layout.
// ---------------------------------------------------------------------------
__global__ __launch_bounds__(256) void attn_mfma(const ushort_t* __restrict__ QR,
                                                 const ushort_t* __restrict__ KR,
                                                 const ushort_t* __restrict__ Vt,
                                                 const unsigned* __restrict__ Mask,
                                                 ushort_t* __restrict__ O)
{
    __shared__ ushort_t Qs[64][136];
    __shared__ ushort_t Ks[64][136];
    __shared__ ushort_t Vs[128][72];
    __shared__ unsigned long long Ms[64];

    const int tid = threadIdx.x;
    const int w = tid >> 6, lane = tid & 63;
    const int ll = lane & 15, lh = lane >> 4;
    const int q0 = blockIdx.x * 64;
    const int h  = blockIdx.y;

#pragma unroll
    for (int i = 0; i < 4; i++) {
        int idx = tid + i * 256;
        int r = idx >> 4, c8 = (idx & 15) * 8;
        *(uint4*)&Qs[r][c8] = *(const uint4*)&QR[(size_t)(q0 + r) * E + h * HD + c8];
    }

    f32x4 Oa[8];
#pragma unroll
    for (int i = 0; i < 8; i++) Oa[i] = f32x4{0.f, 0.f, 0.f, 0.f};
    float mrun = NEGF, lrun = 0.f;
    const float SCL = 0.08838834764831845f * 1.44269504088896f;  // 1/sqrt(128)*log2(e)

    for (int cb = 0; cb <= q0; cb += 64) {
        __syncthreads();
#pragma unroll
        for (int i = 0; i < 4; i++) {
            int idx = tid + i * 256;
            int r = idx >> 4, c8 = (idx & 15) * 8;
            *(uint4*)&Ks[r][c8] = *(const uint4*)&KR[(size_t)(cb + r) * E + h * HD + c8];
        }
#pragma unroll
        for (int i = 0; i < 4; i++) {
            int idx = tid + i * 256;
            int r = idx >> 3, c8 = (idx & 7) * 8;
            *(uint4*)&Vs[r][c8] = *(const uint4*)&Vt[((size_t)h * HD + r) * S + cb + c8];
        }
        if (tid < 64)
            Ms[tid] = *(const unsigned long long*)&Mask[((size_t)h * S + q0 + tid) * 64 + (cb >> 5)];
        __syncthreads();

        // Sc^T[kv][q]: A = K rows (kv), B = Q rows (q). 4 kv-tiles x 4 k-steps.
        f32x4 Sc[4];
#pragma unroll
        for (int t = 0; t < 4; t++) Sc[t] = f32x4{0.f, 0.f, 0.f, 0.f};
#pragma unroll
        for (int kk = 0; kk < 4; kk++) {
            bf16x8 bq = *(const bf16x8*)&Qs[16 * w + ll][kk * 32 + lh * 8];
#pragma unroll
            for (int t = 0; t < 4; t++) {
                bf16x8 ak = *(const bf16x8*)&Ks[t * 16 + ll][kk * 32 + lh * 8];
                Sc[t] = __builtin_amdgcn_mfma_f32_16x16x32_bf16(ak, bq, Sc[t], 0, 0, 0);
            }
        }

        // mask + online softmax (C-layout: col q = ll; row kv = t*16+lh*4+r)
        unsigned long long mrow = Ms[16 * w + ll];
        float sc[4][4];
        float cm = NEGF;
#pragma unroll
        for (int t = 0; t < 4; t++)
#pragma unroll
            for (int r = 0; r < 4; r++) {
                int bit = t * 16 + lh * 4 + r;
                float v = ((mrow >> bit) & 1ull) ? Sc[t][r] * SCL : NEGF;
                sc[t][r] = v;
                cm = fmaxf(cm, v);
            }
        cm = fmaxf(cm, __shfl_xor(cm, 16));
        cm = fmaxf(cm, __shfl_xor(cm, 32));
        float mnew = fmaxf(mrun, cm);
        float alpha = exp2f(mrun - mnew);
        mrun = mnew;
        lrun *= alpha;

        unsigned pk[4][2];
#pragma unroll
        for (int t = 0; t < 4; t++) {
            float p0 = (sc[t][0] > -1e37f) ? exp2f(sc[t][0] - mnew) : 0.f;
            float p1 = (sc[t][1] > -1e37f) ? exp2f(sc[t][1] - mnew) : 0.f;
            float p2 = (sc[t][2] > -1e37f) ? exp2f(sc[t][2] - mnew) : 0.f;
            float p3 = (sc[t][3] > -1e37f) ? exp2f(sc[t][3] - mnew) : 0.f;
            lrun += p0 + p1 + p2 + p3;
            pk[t][0] = (unsigned)f2bf(p0) | ((unsigned)f2bf(p1) << 16);
            pk[t][1] = (unsigned)f2bf(p2) | ((unsigned)f2bf(p3) << 16);
        }
#pragma unroll
        for (int dt = 0; dt < 8; dt++) Oa[dt] *= alpha;

        // PV: O^T[d][q] += V^T-tiles (A, from Vs) x P^T (B, via shuffles)
#pragma unroll
        for (int ks = 0; ks < 2; ks++) {
            union { unsigned u[4]; bf16x8 v; } bu;
#pragma unroll
            for (int jj = 0; jj < 4; jj++) {
                int rp  = jj & 1;
                int src = ll + 16 * ((lh & 1) * 2 + (jj >> 1));
                unsigned v0 = __shfl(pk[ks * 2][rp], src);
                unsigned v1 = __shfl(pk[ks * 2 + 1][rp], src);
                bu.u[jj] = (lh >> 1) ? v1 : v0;
            }
            bf16x8 bp = bu.v;
#pragma unroll
            for (int dt = 0; dt < 8; dt++) {
                bf16x8 av = *(const bf16x8*)&Vs[dt * 16 + ll][ks * 32 + lh * 8];
                Oa[dt] = __builtin_amdgcn_mfma_f32_16x16x32_bf16(av, bp, Oa[dt], 0, 0, 0);
            }
        }
    }

    lrun += __shfl_xor(lrun, 16);
    lrun += __shfl_xor(lrun, 32);
    float linv = 1.0f / lrun;

    __syncthreads();   // all waves done reading Ks/Vs
    ushort_t* tb = &Ks[16 * w][0];   // wave-private 16x136 transpose buffer
#pragma unroll
    for (int dt = 0; dt < 8; dt++)
#pragma unroll
        for (int r = 0; r < 4; r++)
            tb[ll * 136 + dt * 16 + lh * 4 + r] = f2bf(Oa[dt][r] * linv);
#pragma unroll
    for (int i = 0; i < 4; i++) {
        int idx = lane + 64 * i;
        int r = idx >> 4, c8 = (idx & 15) * 8;
        uint4 vv = *(const uint4*)&tb[r * 136 + c8];
        *(uint4*)&O[(size_t)(q0 + 16 * w + r) * E + h * HD + c8] = vv;
    }
}

// ---------------------------------------------------------------------------
extern "C" void kernel_launch(void* const* d_in, const int* in_sizes, int n_in,
                              void* d_out, int out_size, void* d_ws, size_t ws_size,
                              hipStream_t stream)
{
    (void)in_sizes; (void)n_in; (void)out_size; (void)ws_size;
    const float* hidden = (const float*)d_in[0];
    const float* Wq = (const float*)d_in[1];
    const float* Wk = (const float*)d_in[2];
    const float* Wv = (const float*)d_in[3];
    const float* Wo = (const float*)d_in[4];

    float* ws = (float*)d_ws;
    const size_t SE = (size_t)S * E;                    // 8388608
    float*    Qb    = ws;                               // [0, SE) fp32
    float*    Kb    = ws + SE;                          // [SE, 2SE) fp32
    float*    Vb    = ws + 2 * SE;                      // [2SE, 3SE) fp32
    ushort_t* Wt    = (ushort_t*)(ws + 3 * SE);         // [3SE, 4SE) bf16 ExE
    unsigned* Maskb = (unsigned*)(ws + 4 * SE);         // [4SE, 4.5SE)
    ushort_t* Hbf   = (ushort_t*)(ws + 4 * SE + SE / 2);// [4.5SE, 5SE) bf16
    ushort_t* QRbf  = Hbf;                              // reuse after gemmV
    ushort_t* KRbf  = (ushort_t*)(ws + 5 * SE);         // [5SE, 5.5SE) bf16
    ushort_t* Vtbf  = (ushort_t*)Qb;                    // [0, 0.5SE) after rope
    ushort_t* Obf   = (ushort_t*)(ws + SE / 2);         // [0.5SE, SE) after rope
    // total = 5.5*SE floats = 184.5 MB (same footprint as R1)

    dim3 gg(E / 128, S / 128);   // (32,16)

    gemm_fp32<<<gg, 256, 0, stream>>>(hidden, Wq, Qb, S, E, E);
    gemm_fp32<<<gg, 256, 0, stream>>>(hidden, Wk, Kb, S, E, E);

    cvt_bf16<<<SE / 2048, 256, 0, stream>>>(hidden, Hbf);
    transp_cvt<<<dim3(E / 32, E / 32), 256, 0, stream>>>(Wv, Wt);
    gemm_bf16t<<<gg, 256, 0, stream>>>(Hbf, Wt, Vb, S, E, E);

    select_kernel<<<dim3(S / 4, H), 256, 0, stream>>>(Qb, Kb, Maskb);

    rope_bf16<<<(S * 2048) / 256, 256, 0, stream>>>(Qb, Kb, QRbf, KRbf);

    vtransp<<<dim3(E / 32, S / 32), 256, 0, stream>>>(Vb, Vtbf);

    attn_mfma<<<dim3(S / 64, H), 256, 0, stream>>>(QRbf, KRbf, Vtbf, Maskb, Obf);

    transp_cvt<<<dim3(E / 32, E / 32), 256, 0, stream>>>(Wo, Wt);
    gemm_bf16t<<<gg, 256, 0, stream>>>(Obf, Wt, (float*)d_out, S, E, E);
}

// Round 4
// 2272.285 us; speedup vs baseline: 4.6385x; 1.8059x over previous
//
#include <hip/hip_runtime.h>
#include <math.h>

#define S   2048
#define E   4096
#define H   32
#define HD  128
#define NKEEP 205
#define NEGF -3.0e38f

typedef unsigned short ushort_t;
typedef __attribute__((ext_vector_type(8))) __bf16 bf16x8;
typedef __attribute__((ext_vector_type(4))) float f32x4;

__device__ __forceinline__ unsigned fmap(float x) {
    unsigned u = __float_as_uint(x);
    return (u & 0x80000000u) ? ~u : (u | 0x80000000u);
}
__device__ __forceinline__ ushort_t f2bf(float f) {
    unsigned u = __float_as_uint(f);
    u += 0x7FFFu + ((u >> 16) & 1u);
    return (ushort_t)(u >> 16);
}
__device__ __forceinline__ float bf2f(ushort_t h) {
    return __uint_as_float((unsigned)h << 16);
}

// ---------------------------------------------------------------------------
// fp32 -> (hi, lo) bf16 split decomposition, 8 elems/thread
// ---------------------------------------------------------------------------
__global__ __launch_bounds__(256) void decomp(const float* __restrict__ in,
                                              ushort_t* __restrict__ hi,
                                              ushort_t* __restrict__ lo)
{
    size_t i8 = ((size_t)blockIdx.x * 256 + threadIdx.x) * 8;
    float x[8];
    *(float4*)&x[0] = *(const float4*)&in[i8];
    *(float4*)&x[4] = *(const float4*)&in[i8 + 4];
    ushort_t rh[8], rl[8];
#pragma unroll
    for (int i = 0; i < 8; i++) {
        ushort_t h = f2bf(x[i]);
        rh[i] = h;
        rl[i] = f2bf(x[i] - bf2f(h));
    }
    *(uint4*)&hi[i8] = *(uint4*)rh;
    *(uint4*)&lo[i8] = *(uint4*)rl;
}

// ---------------------------------------------------------------------------
// W fp32 [K][N] -> bf16 split W^T: Wth/Wtl [N][K]  (32x32 tile transpose)
// ---------------------------------------------------------------------------
__global__ __launch_bounds__(256) void transp_decomp(const float* __restrict__ W,
                                                     ushort_t* __restrict__ Wth,
                                                     ushort_t* __restrict__ Wtl)
{
    __shared__ ushort_t th[32][34];
    __shared__ ushort_t tl[32][34];
    const int tid = threadIdx.x;
    const int k0 = blockIdx.y * 32, n0 = blockIdx.x * 32;
    const int row = tid >> 3, c4 = (tid & 7) * 4;
    float4 v = *(const float4*)&W[(size_t)(k0 + row) * E + n0 + c4];
    float x[4] = { v.x, v.y, v.z, v.w };
#pragma unroll
    for (int i = 0; i < 4; i++) {
        ushort_t h = f2bf(x[i]);
        th[row][c4 + i] = h;
        tl[row][c4 + i] = f2bf(x[i] - bf2f(h));
    }
    __syncthreads();
    ushort_t oh[4], ol[4];
#pragma unroll
    for (int i = 0; i < 4; i++) {
        oh[i] = th[c4 + i][row];
        ol[i] = tl[c4 + i][row];
    }
    *((uint2*)&Wth[(size_t)(n0 + row) * E + k0 + c4]) = *(uint2*)oh;
    *((uint2*)&Wtl[(size_t)(n0 + row) * E + k0 + c4]) = *(uint2*)ol;
}

// ---------------------------------------------------------------------------
// W fp32 [K][N] -> plain bf16 W^T [N][K]  (for Wv / Wo)
// ---------------------------------------------------------------------------
__global__ __launch_bounds__(256) void transp_cvt(const float* __restrict__ W,
                                                  ushort_t* __restrict__ Wt)
{
    __shared__ ushort_t tile[32][34];
    const int tid = threadIdx.x;
    const int k0 = blockIdx.y * 32, n0 = blockIdx.x * 32;
    const int row = tid >> 3, c4 = (tid & 7) * 4;
    float4 v = *(const float4*)&W[(size_t)(k0 + row) * E + n0 + c4];
    tile[row][c4 + 0] = f2bf(v.x);
    tile[row][c4 + 1] = f2bf(v.y);
    tile[row][c4 + 2] = f2bf(v.z);
    tile[row][c4 + 3] = f2bf(v.w);
    __syncthreads();
    ushort_t o[4] = { tile[c4 + 0][row], tile[c4 + 1][row],
                      tile[c4 + 2][row], tile[c4 + 3][row] };
    *((uint2*)&Wt[(size_t)(n0 + row) * E + k0 + c4]) = *(uint2*)o;
}

// ---------------------------------------------------------------------------
// Split-bf16 MFMA GEMM (fp32-accuracy): C = (Ah+Al) x (Bh+Bl)^T, dropping
// Al*Bl (~2^-16 rel). Output as hi/lo bf16 split. 128x128 tile, BK=32.
// ---------------------------------------------------------------------------
__global__ __launch_bounds__(256) void gemm_split(const ushort_t* __restrict__ Ah,
                                                  const ushort_t* __restrict__ Al,
                                                  const ushort_t* __restrict__ Bh,
                                                  const ushort_t* __restrict__ Bl,
                                                  ushort_t* __restrict__ Chi,
                                                  ushort_t* __restrict__ Clo,
                                                  int M, int N, int Kd)
{
    __shared__ ushort_t AsH[128 * 40];
    __shared__ ushort_t AsL[128 * 40];
    __shared__ ushort_t BsH[128 * 40];
    __shared__ ushort_t BsL[128 * 40];
    const int tid = threadIdx.x;
    const int m0 = blockIdx.y * 128, n0 = blockIdx.x * 128;
    const int lane = tid & 63, w = tid >> 6;
    const int wm = (w & 1) * 64, wn = (w >> 1) * 64;
    const int ll = lane & 15, lh = lane >> 4;
    const int srow = tid >> 2, sk = (tid & 3) * 8;

    f32x4 acc[4][4];
#pragma unroll
    for (int i = 0; i < 4; i++)
#pragma unroll
        for (int j = 0; j < 4; j++) acc[i][j] = f32x4{0.f, 0.f, 0.f, 0.f};

    const size_t aoff = (size_t)(m0 + srow) * Kd + sk;
    const size_t boff = (size_t)(n0 + srow) * Kd + sk;
    const size_t roff = (size_t)64 * Kd;

    for (int k0 = 0; k0 < Kd; k0 += 32) {
        uint4 avh0 = *(const uint4*)(Ah + aoff + k0);
        uint4 avh1 = *(const uint4*)(Ah + aoff + k0 + roff);
        uint4 avl0 = *(const uint4*)(Al + aoff + k0);
        uint4 avl1 = *(const uint4*)(Al + aoff + k0 + roff);
        uint4 bvh0 = *(const uint4*)(Bh + boff + k0);
        uint4 bvh1 = *(const uint4*)(Bh + boff + k0 + roff);
        uint4 bvl0 = *(const uint4*)(Bl + boff + k0);
        uint4 bvl1 = *(const uint4*)(Bl + boff + k0 + roff);
        __syncthreads();
        *(uint4*)&AsH[srow * 40 + sk]        = avh0;
        *(uint4*)&AsH[(srow + 64) * 40 + sk] = avh1;
        *(uint4*)&AsL[srow * 40 + sk]        = avl0;
        *(uint4*)&AsL[(srow + 64) * 40 + sk] = avl1;
        *(uint4*)&BsH[srow * 40 + sk]        = bvh0;
        *(uint4*)&BsH[(srow + 64) * 40 + sk] = bvh1;
        *(uint4*)&BsL[srow * 40 + sk]        = bvl0;
        *(uint4*)&BsL[(srow + 64) * 40 + sk] = bvl1;
        __syncthreads();

        bf16x8 afh[4], afl[4], bfh[4], bfl[4];
#pragma unroll
        for (int i = 0; i < 4; i++) {
            afh[i] = *(const bf16x8*)&AsH[(wm + 16 * i + ll) * 40 + lh * 8];
            afl[i] = *(const bf16x8*)&AsL[(wm + 16 * i + ll) * 40 + lh * 8];
        }
#pragma unroll
        for (int j = 0; j < 4; j++) {
            bfh[j] = *(const bf16x8*)&BsH[(wn + 16 * j + ll) * 40 + lh * 8];
            bfl[j] = *(const bf16x8*)&BsL[(wn + 16 * j + ll) * 40 + lh * 8];
        }
#pragma unroll
        for (int i = 0; i < 4; i++)
#pragma unroll
            for (int j = 0; j < 4; j++) {
                acc[i][j] = __builtin_amdgcn_mfma_f32_16x16x32_bf16(afh[i], bfh[j], acc[i][j], 0, 0, 0);
                acc[i][j] = __builtin_amdgcn_mfma_f32_16x16x32_bf16(afh[i], bfl[j], acc[i][j], 0, 0, 0);
                acc[i][j] = __builtin_amdgcn_mfma_f32_16x16x32_bf16(afl[i], bfh[j], acc[i][j], 0, 0, 0);
            }
    }
#pragma unroll
    for (int i = 0; i < 4; i++)
#pragma unroll
        for (int j = 0; j < 4; j++)
#pragma unroll
            for (int r = 0; r < 4; r++) {
                float v = acc[i][j][r];
                ushort_t h = f2bf(v);
                ushort_t l = f2bf(v - bf2f(h));
                size_t idx = (size_t)(m0 + wm + 16 * i + lh * 4 + r) * N + (n0 + wn + 16 * j + ll);
                Chi[idx] = h;
                Clo[idx] = l;
            }
}

// ---------------------------------------------------------------------------
// Plain bf16 MFMA GEMM -> fp32 C (O projection)
// ---------------------------------------------------------------------------
__global__ __launch_bounds__(256) void gemm_bf16t(const ushort_t* __restrict__ A,
                                                  const ushort_t* __restrict__ Bt,
                                                  float* __restrict__ C,
                                                  int M, int N, int Kd)
{
    __shared__ ushort_t As[128 * 40];
    __shared__ ushort_t Bs[128 * 40];
    const int tid = threadIdx.x;
    const int m0 = blockIdx.y * 128, n0 = blockIdx.x * 128;
    const int lane = tid & 63, w = tid >> 6;
    const int wm = (w & 1) * 64, wn = (w >> 1) * 64;
    const int ll = lane & 15, lh = lane >> 4;
    const int srow = tid >> 2, sk = (tid & 3) * 8;

    f32x4 acc[4][4];
#pragma unroll
    for (int i = 0; i < 4; i++)
#pragma unroll
        for (int j = 0; j < 4; j++) acc[i][j] = f32x4{0.f, 0.f, 0.f, 0.f};

    const ushort_t* Ap = A + (size_t)(m0 + srow) * Kd + sk;
    const ushort_t* Bp = Bt + (size_t)(n0 + srow) * Kd + sk;

    for (int k0 = 0; k0 < Kd; k0 += 32) {
        uint4 av0 = *(const uint4*)(Ap + k0);
        uint4 av1 = *(const uint4*)(Ap + k0 + (size_t)64 * Kd);
        uint4 bv0 = *(const uint4*)(Bp + k0);
        uint4 bv1 = *(const uint4*)(Bp + k0 + (size_t)64 * Kd);
        __syncthreads();
        *(uint4*)&As[srow * 40 + sk]        = av0;
        *(uint4*)&As[(srow + 64) * 40 + sk] = av1;
        *(uint4*)&Bs[srow * 40 + sk]        = bv0;
        *(uint4*)&Bs[(srow + 64) * 40 + sk] = bv1;
        __syncthreads();

        bf16x8 af[4], bfr[4];
#pragma unroll
        for (int i = 0; i < 4; i++)
            af[i] = *(const bf16x8*)&As[(wm + 16 * i + ll) * 40 + lh * 8];
#pragma unroll
        for (int j = 0; j < 4; j++)
            bfr[j] = *(const bf16x8*)&Bs[(wn + 16 * j + ll) * 40 + lh * 8];
#pragma unroll
        for (int i = 0; i < 4; i++)
#pragma unroll
            for (int j = 0; j < 4; j++)
                acc[i][j] = __builtin_amdgcn_mfma_f32_16x16x32_bf16(af[i], bfr[j], acc[i][j], 0, 0, 0);
    }
#pragma unroll
    for (int i = 0; i < 4; i++)
#pragma unroll
        for (int j = 0; j < 4; j++)
#pragma unroll
            for (int r = 0; r < 4; r++)
                C[(size_t)(m0 + wm + 16 * i + lh * 4 + r) * N + (n0 + wn + 16 * j + ll)] = acc[i][j][r];
}

// ---------------------------------------------------------------------------
// Plain bf16 MFMA GEMM -> bf16 C^T  (V projection, writes Vt[e][s] directly)
// ---------------------------------------------------------------------------
__global__ __launch_bounds__(256) void gemm_bf16_vt(const ushort_t* __restrict__ A,
                                                    const ushort_t* __restrict__ Bt,
                                                    ushort_t* __restrict__ Ct,
                                                    int M, int N, int Kd)
{
    __shared__ ushort_t As[128 * 40];
    __shared__ ushort_t Bs[128 * 40];
    const int tid = threadIdx.x;
    const int m0 = blockIdx.y * 128, n0 = blockIdx.x * 128;
    const int lane = tid & 63, w = tid >> 6;
    const int wm = (w & 1) * 64, wn = (w >> 1) * 64;
    const int ll = lane & 15, lh = lane >> 4;
    const int srow = tid >> 2, sk = (tid & 3) * 8;

    f32x4 acc[4][4];
#pragma unroll
    for (int i = 0; i < 4; i++)
#pragma unroll
        for (int j = 0; j < 4; j++) acc[i][j] = f32x4{0.f, 0.f, 0.f, 0.f};

    const ushort_t* Ap = A + (size_t)(m0 + srow) * Kd + sk;
    const ushort_t* Bp = Bt + (size_t)(n0 + srow) * Kd + sk;

    for (int k0 = 0; k0 < Kd; k0 += 32) {
        uint4 av0 = *(const uint4*)(Ap + k0);
        uint4 av1 = *(const uint4*)(Ap + k0 + (size_t)64 * Kd);
        uint4 bv0 = *(const uint4*)(Bp + k0);
        uint4 bv1 = *(const uint4*)(Bp + k0 + (size_t)64 * Kd);
        __syncthreads();
        *(uint4*)&As[srow * 40 + sk]        = av0;
        *(uint4*)&As[(srow + 64) * 40 + sk] = av1;
        *(uint4*)&Bs[srow * 40 + sk]        = bv0;
        *(uint4*)&Bs[(srow + 64) * 40 + sk] = bv1;
        __syncthreads();

        bf16x8 af[4], bfr[4];
#pragma unroll
        for (int i = 0; i < 4; i++)
            af[i] = *(const bf16x8*)&As[(wm + 16 * i + ll) * 40 + lh * 8];
#pragma unroll
        for (int j = 0; j < 4; j++)
            bfr[j] = *(const bf16x8*)&Bs[(wn + 16 * j + ll) * 40 + lh * 8];
#pragma unroll
        for (int i = 0; i < 4; i++)
#pragma unroll
            for (int j = 0; j < 4; j++)
                acc[i][j] = __builtin_amdgcn_mfma_f32_16x16x32_bf16(af[i], bfr[j], acc[i][j], 0, 0, 0);
    }
    // write C^T: Ct[n][m], 4 consecutive m per lane -> 8B stores
#pragma unroll
    for (int i = 0; i < 4; i++)
#pragma unroll
        for (int j = 0; j < 4; j++) {
            ushort_t o4[4];
#pragma unroll
            for (int r = 0; r < 4; r++) o4[r] = f2bf(acc[i][j][r]);
            size_t n = n0 + wn + 16 * j + ll;
            size_t m = m0 + wm + 16 * i + lh * 4;
            *(uint2*)&Ct[n * M + m] = *(uint2*)o4;
        }
}

// ---------------------------------------------------------------------------
// RoPE from hi/lo split Q/K -> bf16 QR/KR
// ---------------------------------------------------------------------------
__global__ __launch_bounds__(256) void rope_split(const ushort_t* __restrict__ Qh,
                                                  const ushort_t* __restrict__ Ql,
                                                  const ushort_t* __restrict__ Kh,
                                                  const ushort_t* __restrict__ Kl,
                                                  ushort_t* __restrict__ QR,
                                                  ushort_t* __restrict__ KR)
{
    int idx = blockIdx.x * 256 + threadIdx.x;
    int s   = idx >> 11;
    int rem = idx & 2047;
    int h   = rem >> 6;
    int d   = rem & 63;
    float inv = exp2f(-0.20762050593046f * (float)d);
    float ang = (float)s * inv;
    float sn, cs;
    sincosf(ang, &sn, &cs);
    size_t base = (size_t)s * E + h * HD;
    float q0 = bf2f(Qh[base + d])      + bf2f(Ql[base + d]);
    float q1 = bf2f(Qh[base + d + 64]) + bf2f(Ql[base + d + 64]);
    QR[base + d]      = f2bf(q0 * cs - q1 * sn);
    QR[base + d + 64] = f2bf(q1 * cs + q0 * sn);
    float k0 = bf2f(Kh[base + d])      + bf2f(Kl[base + d]);
    float k1 = bf2f(Kh[base + d + 64]) + bf2f(Kl[base + d + 64]);
    KR[base + d]      = f2bf(k0 * cs - k1 * sn);
    KR[base + d + 64] = f2bf(k1 * cs + k0 * sn);
}

// ---------------------------------------------------------------------------
// MFMA selection: block = 16 q-rows x 1 head, 4 waves. Draft scores via
// split-bf16 3-MFMA (Sc^T = K.Q^T) into full-row LDS (xor-swizzled, fmap'd
// u32), then wave-private exact 32-bit radix select + ballot mask write.
// LDS = 128K scores + 2x16K K staging = 160 KB exactly (1 block/CU).
// ---------------------------------------------------------------------------
__global__ __launch_bounds__(256) void select_mfma(const ushort_t* __restrict__ Qhi,
                                                   const ushort_t* __restrict__ Qlo,
                                                   const ushort_t* __restrict__ Khi,
                                                   const ushort_t* __restrict__ Klo,
                                                   unsigned* __restrict__ Mask)
{
    __shared__ unsigned scores[16 * 2048];   // 131072 B
    __shared__ ushort_t KsHi[64 * 128];      // 16384 B (xor-swizzled 16B blocks)
    __shared__ ushort_t KsLo[64 * 128];      // 16384 B

    const int tid = threadIdx.x;
    const int w = tid >> 6, lane = tid & 63;
    const int ll = lane & 15, lh = lane >> 4;
    const int q0 = blockIdx.x * 16;
    const int h  = blockIdx.y;

    // B-frags: Q rows q0+ll (hi/lo), straight from global (one-time 16 KB)
    bf16x8 bqh[4], bql[4];
    const size_t qbase = (size_t)(q0 + ll) * E + h * HD;
#pragma unroll
    for (int ks = 0; ks < 4; ks++) {
        bqh[ks] = *(const bf16x8*)&Qhi[qbase + ks * 32 + lh * 8];
        bql[ks] = *(const bf16x8*)&Qlo[qbase + ks * 32 + lh * 8];
    }

    {   // zero scores (cols beyond causal range must read 0 = masked)
        uint4* sv = (uint4*)scores;
        uint4 z = make_uint4(0u, 0u, 0u, 0u);
        for (int i = tid; i < 16 * 2048 / 4; i += 256) sv[i] = z;
    }

    const int qend = q0 + 16;
    for (int cb = 0; cb < qend; cb += 64) {
#pragma unroll
        for (int i = 0; i < 4; i++) {
            int idx = tid + (i << 8);           // 1024 16B-blocks
            int r = idx >> 4, j = idx & 15;
            int dst = r * 128 + ((j ^ (r & 7)) << 3);
            const size_t src = (size_t)(cb + r) * E + h * HD + j * 8;
            *(uint4*)&KsHi[dst] = *(const uint4*)&Khi[src];
            *(uint4*)&KsLo[dst] = *(const uint4*)&Klo[src];
        }
        __syncthreads();

        f32x4 acc = f32x4{0.f, 0.f, 0.f, 0.f};
        const int rrow = w * 16 + ll;
#pragma unroll
        for (int ks = 0; ks < 4; ks++) {
            int blk = ((ks * 4 + lh) ^ (rrow & 7)) << 3;
            bf16x8 akh = *(const bf16x8*)&KsHi[rrow * 128 + blk];
            bf16x8 akl = *(const bf16x8*)&KsLo[rrow * 128 + blk];
            acc = __builtin_amdgcn_mfma_f32_16x16x32_bf16(akh, bqh[ks], acc, 0, 0, 0);
            acc = __builtin_amdgcn_mfma_f32_16x16x32_bf16(akh, bql[ks], acc, 0, 0, 0);
            acc = __builtin_amdgcn_mfma_f32_16x16x32_bf16(akl, bqh[ks], acc, 0, 0, 0);
        }
        // C-layout: q col = ll, kv row = w*16 + lh*4 + r
        const int qrow_g = q0 + ll;
        const int swz = (ll & 7) * 4;
#pragma unroll
        for (int r = 0; r < 4; r++) {
            int col = cb + w * 16 + lh * 4 + r;
            unsigned val = (col <= qrow_g) ? fmap(acc[r]) : 0u;
            scores[ll * 2048 + (col ^ swz)] = val;
        }
        __syncthreads();
    }

    // ---- radix phase: wave w handles q-rows w*4 .. w*4+3 (K LDS now dead) ----
    unsigned* hist = (unsigned*)KsHi + w * 256;
    for (int t = 0; t < 4; t++) {
        const int qq = w * 4 + t;
        const int qrow = q0 + qq;
        const unsigned* srow = &scores[qq * 2048];
        const int swz = (qq & 7) * 4;
        const int Vn = qrow + 1;
        unsigned thr = 1u;
        if (Vn > NKEEP) {
            unsigned p = 0u, need = NKEEP;
            for (int pass = 0; pass < 4; pass++) {
                const int shift = 24 - 8 * pass;
                *(uint4*)&hist[lane * 4] = make_uint4(0u, 0u, 0u, 0u);
                __threadfence_block();
                for (int i = 0; i < 32; i++) {
                    unsigned v = srow[lane + (i << 6)];
                    bool part = (pass == 0) ? true : ((v >> (shift + 8)) == p);
                    if (part) atomicAdd(&hist[(v >> shift) & 255u], 1u);
                }
                __threadfence_block();
                uint4 hv = *(const uint4*)&hist[lane * 4];
                unsigned t3 = hv.w;
                unsigned t2 = t3 + hv.z;
                unsigned t1 = t2 + hv.y;
                unsigned t0 = t1 + hv.x;
                unsigned sv = t0;
                unsigned run = sv;
#pragma unroll
                for (int off = 1; off < 64; off <<= 1) {
                    unsigned o = __shfl_down(run, off);
                    if (lane + off < 64) run += o;
                }
                const unsigned nxt = run - sv;
                unsigned tj[4] = { t0, t1, t2, t3 };
                bool m = false; unsigned nb = 0u, nn = 0u;
#pragma unroll
                for (int j = 0; j < 4; j++) {
                    unsigned sb  = nxt + tj[j];
                    unsigned sb1 = nxt + ((j < 3) ? tj[j + 1] : 0u);
                    if (!m && need <= sb && need > sb1) {
                        m = true; nb = (unsigned)(lane * 4 + j); nn = need - sb1;
                    }
                }
                unsigned long long bal = __ballot(m);
                int src = __ffsll(bal) - 1;
                p    = (p << 8) | __shfl(nb, src);
                need = __shfl(nn, src);
            }
            thr = p;
        }
        const size_t mbase = ((size_t)h * S + qrow) * 64;
        for (int base = 0; base < S; base += 64) {
            bool keep = srow[base + (lane ^ swz)] >= thr;
            unsigned long long bm = __ballot(keep);
            if (lane == 0) {
                Mask[mbase + (base >> 5)]     = (unsigned)bm;
                Mask[mbase + (base >> 5) + 1] = (unsigned)(bm >> 32);
            }
        }
    }
}

// ---------------------------------------------------------------------------
// MFMA flash attention (unchanged from R3)
// ---------------------------------------------------------------------------
__global__ __launch_bounds__(256) void attn_mfma(const ushort_t* __restrict__ QR,
                                                 const ushort_t* __restrict__ KR,
                                                 const ushort_t* __restrict__ Vt,
                                                 const unsigned* __restrict__ Mask,
                                                 ushort_t* __restrict__ O)
{
    __shared__ ushort_t Qs[64][136];
    __shared__ ushort_t Ks[64][136];
    __shared__ ushort_t Vs[128][72];
    __shared__ unsigned long long Ms[64];

    const int tid = threadIdx.x;
    const int w = tid >> 6, lane = tid & 63;
    const int ll = lane & 15, lh = lane >> 4;
    const int q0 = blockIdx.x * 64;
    const int h  = blockIdx.y;

#pragma unroll
    for (int i = 0; i < 4; i++) {
        int idx = tid + i * 256;
        int r = idx >> 4, c8 = (idx & 15) * 8;
        *(uint4*)&Qs[r][c8] = *(const uint4*)&QR[(size_t)(q0 + r) * E + h * HD + c8];
    }

    f32x4 Oa[8];
#pragma unroll
    for (int i = 0; i < 8; i++) Oa[i] = f32x4{0.f, 0.f, 0.f, 0.f};
    float mrun = NEGF, lrun = 0.f;
    const float SCL = 0.08838834764831845f * 1.44269504088896f;

    for (int cb = 0; cb <= q0; cb += 64) {
        __syncthreads();
#pragma unroll
        for (int i = 0; i < 4; i++) {
            int idx = tid + i * 256;
            int r = idx >> 4, c8 = (idx & 15) * 8;
            *(uint4*)&Ks[r][c8] = *(const uint4*)&KR[(size_t)(cb + r) * E + h * HD + c8];
        }
#pragma unroll
        for (int i = 0; i < 4; i++) {
            int idx = tid + i * 256;
            int r = idx >> 3, c8 = (idx & 7) * 8;
            *(uint4*)&Vs[r][c8] = *(const uint4*)&Vt[((size_t)h * HD + r) * S + cb + c8];
        }
        if (tid < 64)
            Ms[tid] = *(const unsigned long long*)&Mask[((size_t)h * S + q0 + tid) * 64 + (cb >> 5)];
        __syncthreads();

        f32x4 Sc[4];
#pragma unroll
        for (int t = 0; t < 4; t++) Sc[t] = f32x4{0.f, 0.f, 0.f, 0.f};
#pragma unroll
        for (int kk = 0; kk < 4; kk++) {
            bf16x8 bq = *(const bf16x8*)&Qs[16 * w + ll][kk * 32 + lh * 8];
#pragma unroll
            for (int t = 0; t < 4; t++) {
                bf16x8 ak = *(const bf16x8*)&Ks[t * 16 + ll][kk * 32 + lh * 8];
                Sc[t] = __builtin_amdgcn_mfma_f32_16x16x32_bf16(ak, bq, Sc[t], 0, 0, 0);
            }
        }

        unsigned long long mrow = Ms[16 * w + ll];
        float sc[4][4];
        float cm = NEGF;
#pragma unroll
        for (int t = 0; t < 4; t++)
#pragma unroll
            for (int r = 0; r < 4; r++) {
                int bit = t * 16 + lh * 4 + r;
                float v = ((mrow >> bit) & 1ull) ? Sc[t][r] * SCL : NEGF;
                sc[t][r] = v;
                cm = fmaxf(cm, v);
            }
        cm = fmaxf(cm, __shfl_xor(cm, 16));
        cm = fmaxf(cm, __shfl_xor(cm, 32));
        float mnew = fmaxf(mrun, cm);
        float alpha = exp2f(mrun - mnew);
        mrun = mnew;
        lrun *= alpha;

        unsigned pk[4][2];
#pragma unroll
        for (int t = 0; t < 4; t++) {
            float p0 = (sc[t][0] > -1e37f) ? exp2f(sc[t][0] - mnew) : 0.f;
            float p1 = (sc[t][1] > -1e37f) ? exp2f(sc[t][1] - mnew) : 0.f;
            float p2 = (sc[t][2] > -1e37f) ? exp2f(sc[t][2] - mnew) : 0.f;
            float p3 = (sc[t][3] > -1e37f) ? exp2f(sc[t][3] - mnew) : 0.f;
            lrun += p0 + p1 + p2 + p3;
            pk[t][0] = (unsigned)f2bf(p0) | ((unsigned)f2bf(p1) << 16);
            pk[t][1] = (unsigned)f2bf(p2) | ((unsigned)f2bf(p3) << 16);
        }
#pragma unroll
        for (int dt = 0; dt < 8; dt++) Oa[dt] *= alpha;

#pragma unroll
        for (int ks = 0; ks < 2; ks++) {
            union { unsigned u[4]; bf16x8 v; } bu;
#pragma unroll
            for (int jj = 0; jj < 4; jj++) {
                int rp  = jj & 1;
                int src = ll + 16 * ((lh & 1) * 2 + (jj >> 1));
                unsigned v0 = __shfl(pk[ks * 2][rp], src);
                unsigned v1 = __shfl(pk[ks * 2 + 1][rp], src);
                bu.u[jj] = (lh >> 1) ? v1 : v0;
            }
            bf16x8 bp = bu.v;
#pragma unroll
            for (int dt = 0; dt < 8; dt++) {
                bf16x8 av = *(const bf16x8*)&Vs[dt * 16 + ll][ks * 32 + lh * 8];
                Oa[dt] = __builtin_amdgcn_mfma_f32_16x16x32_bf16(av, bp, Oa[dt], 0, 0, 0);
            }
        }
    }

    lrun += __shfl_xor(lrun, 16);
    lrun += __shfl_xor(lrun, 32);
    float linv = 1.0f / lrun;

    __syncthreads();
    ushort_t* tb = &Ks[16 * w][0];
#pragma unroll
    for (int dt = 0; dt < 8; dt++)
#pragma unroll
        for (int r = 0; r < 4; r++)
            tb[ll * 136 + dt * 16 + lh * 4 + r] = f2bf(Oa[dt][r] * linv);
#pragma unroll
    for (int i = 0; i < 4; i++) {
        int idx = lane + 64 * i;
        int r = idx >> 4, c8 = (idx & 15) * 8;
        uint4 vv = *(const uint4*)&tb[r * 136 + c8];
        *(uint4*)&O[(size_t)(q0 + 16 * w + r) * E + h * HD + c8] = vv;
    }
}

// ---------------------------------------------------------------------------
extern "C" void kernel_launch(void* const* d_in, const int* in_sizes, int n_in,
                              void* d_out, int out_size, void* d_ws, size_t ws_size,
                              hipStream_t stream)
{
    (void)in_sizes; (void)n_in; (void)out_size; (void)ws_size;
    const float* hidden = (const float*)d_in[0];
    const float* Wq = (const float*)d_in[1];
    const float* Wk = (const float*)d_in[2];
    const float* Wv = (const float*)d_in[3];
    const float* Wo = (const float*)d_in[4];

    float* ws = (float*)d_ws;
    const size_t SE = (size_t)S * E;   // 8388608
    // float-unit offsets (1 SE-float-unit = 33.55 MB):
    ushort_t* Hhi  = (ushort_t*)ws;                      // [0,   .5SE)
    ushort_t* Hlo  = (ushort_t*)(ws + SE / 2);           // [.5,  1SE)  -> later Obf
    ushort_t* WtH  = (ushort_t*)(ws + SE);               // [1,   2SE)  Wq/Wk hi -> later Wt (Wv/Wo)
    ushort_t* WtL  = (ushort_t*)(ws + 2 * SE);           // [2,   3SE)  Wq/Wk lo -> later QR/KR
    ushort_t* Qhi  = (ushort_t*)(ws + 3 * SE);           // [3,  3.5SE)
    ushort_t* Qlo  = (ushort_t*)(ws + 3 * SE + SE / 2);  // [3.5, 4SE)
    ushort_t* Khi  = (ushort_t*)(ws + 4 * SE);           // [4,  4.5SE)
    ushort_t* Klo  = (ushort_t*)(ws + 4 * SE + SE / 2);  // [4.5, 5SE)
    unsigned* Maskb= (unsigned*)(ws + 5 * SE);           // [5,  5.5SE)
    ushort_t* Vtbf = (ushort_t*)(ws + 5 * SE + SE / 2);  // [5.5, 6SE)
    ushort_t* QRbf = WtL;                                // after gemm_split K
    ushort_t* KRbf = (ushort_t*)(ws + 2 * SE + SE / 2);
    ushort_t* Obf  = Hlo;                                // after gemm_splits
    ushort_t* Wt   = WtH;                                // after gemm_split K
    // total = 6 SE floats = 201 MB

    dim3 gg(E / 128, S / 128);           // (32,16)
    dim3 gt(E / 32, E / 32);             // (128,128)

    decomp<<<SE / 2048, 256, 0, stream>>>(hidden, Hhi, Hlo);

    transp_decomp<<<gt, 256, 0, stream>>>(Wq, WtH, WtL);
    gemm_split<<<gg, 256, 0, stream>>>(Hhi, Hlo, WtH, WtL, Qhi, Qlo, S, E, E);
    transp_decomp<<<gt, 256, 0, stream>>>(Wk, WtH, WtL);
    gemm_split<<<gg, 256, 0, stream>>>(Hhi, Hlo, WtH, WtL, Khi, Klo, S, E, E);

    select_mfma<<<dim3(S / 16, H), 256, 0, stream>>>(Qhi, Qlo, Khi, Klo, Maskb);

    rope_split<<<(S * 2048) / 256, 256, 0, stream>>>(Qhi, Qlo, Khi, Klo, QRbf, KRbf);

    transp_cvt<<<gt, 256, 0, stream>>>(Wv, Wt);
    gemm_bf16_vt<<<gg, 256, 0, stream>>>(Hhi, Wt, Vtbf, S, E, E);

    attn_mfma<<<dim3(S / 64, H), 256, 0, stream>>>(QRbf, KRbf, Vtbf, Maskb, Obf);

    transp_cvt<<<gt, 256, 0, stream>>>(Wo, Wt);
    gemm_bf16t<<<gg, 256, 0, stream>>>(Obf, Wt, (float*)d_out, S, E, E);
}

// Round 5
// 1903.940 us; speedup vs baseline: 5.5359x; 1.1935x over previous
//
#include <hip/hip_runtime.h>
#include <math.h>

#define S   2048
#define E   4096
#define H   32
#define HD  128
#define NKEEP 205
#define NEGF -3.0e38f

typedef unsigned short ushort_t;
typedef __attribute__((ext_vector_type(8))) __bf16 bf16x8;
typedef __attribute__((ext_vector_type(4))) float f32x4;

__device__ __forceinline__ unsigned fmap(float x) {
    unsigned u = __float_as_uint(x);
    return (u & 0x80000000u) ? ~u : (u | 0x80000000u);
}
__device__ __forceinline__ ushort_t f2bf(float f) {
    unsigned u = __float_as_uint(f);
    u += 0x7FFFu + ((u >> 16) & 1u);
    return (ushort_t)(u >> 16);
}
__device__ __forceinline__ float bf2f(ushort_t h) {
    return __uint_as_float((unsigned)h << 16);
}

// ---------------------------------------------------------------------------
// fp32 -> (hi, lo) bf16 split decomposition, 8 elems/thread
// ---------------------------------------------------------------------------
__global__ __launch_bounds__(256) void decomp(const float* __restrict__ in,
                                              ushort_t* __restrict__ hi,
                                              ushort_t* __restrict__ lo)
{
    size_t i8 = ((size_t)blockIdx.x * 256 + threadIdx.x) * 8;
    float x[8];
    *(float4*)&x[0] = *(const float4*)&in[i8];
    *(float4*)&x[4] = *(const float4*)&in[i8 + 4];
    ushort_t rh[8], rl[8];
#pragma unroll
    for (int i = 0; i < 8; i++) {
        ushort_t h = f2bf(x[i]);
        rh[i] = h;
        rl[i] = f2bf(x[i] - bf2f(h));
    }
    *(uint4*)&hi[i8] = *(uint4*)rh;
    *(uint4*)&lo[i8] = *(uint4*)rl;
}

// ---------------------------------------------------------------------------
// W fp32 [K][N] -> bf16 split W^T: Wth/Wtl [N][K]  (32x32 tile transpose)
// ---------------------------------------------------------------------------
__global__ __launch_bounds__(256) void transp_decomp(const float* __restrict__ W,
                                                     ushort_t* __restrict__ Wth,
                                                     ushort_t* __restrict__ Wtl)
{
    __shared__ ushort_t th[32][34];
    __shared__ ushort_t tl[32][34];
    const int tid = threadIdx.x;
    const int k0 = blockIdx.y * 32, n0 = blockIdx.x * 32;
    const int row = tid >> 3, c4 = (tid & 7) * 4;
    float4 v = *(const float4*)&W[(size_t)(k0 + row) * E + n0 + c4];
    float x[4] = { v.x, v.y, v.z, v.w };
#pragma unroll
    for (int i = 0; i < 4; i++) {
        ushort_t h = f2bf(x[i]);
        th[row][c4 + i] = h;
        tl[row][c4 + i] = f2bf(x[i] - bf2f(h));
    }
    __syncthreads();
    ushort_t oh[4], ol[4];
#pragma unroll
    for (int i = 0; i < 4; i++) {
        oh[i] = th[c4 + i][row];
        ol[i] = tl[c4 + i][row];
    }
    *((uint2*)&Wth[(size_t)(n0 + row) * E + k0 + c4]) = *(uint2*)oh;
    *((uint2*)&Wtl[(size_t)(n0 + row) * E + k0 + c4]) = *(uint2*)ol;
}

// ---------------------------------------------------------------------------
// W fp32 [K][N] -> plain bf16 W^T [N][K]  (for Wv / Wo)
// ---------------------------------------------------------------------------
__global__ __launch_bounds__(256) void transp_cvt(const float* __restrict__ W,
                                                  ushort_t* __restrict__ Wt)
{
    __shared__ ushort_t tile[32][34];
    const int tid = threadIdx.x;
    const int k0 = blockIdx.y * 32, n0 = blockIdx.x * 32;
    const int row = tid >> 3, c4 = (tid & 7) * 4;
    float4 v = *(const float4*)&W[(size_t)(k0 + row) * E + n0 + c4];
    tile[row][c4 + 0] = f2bf(v.x);
    tile[row][c4 + 1] = f2bf(v.y);
    tile[row][c4 + 2] = f2bf(v.z);
    tile[row][c4 + 3] = f2bf(v.w);
    __syncthreads();
    ushort_t o[4] = { tile[c4 + 0][row], tile[c4 + 1][row],
                      tile[c4 + 2][row], tile[c4 + 3][row] };
    *((uint2*)&Wt[(size_t)(n0 + row) * E + k0 + c4]) = *(uint2*)o;
}

// ---------------------------------------------------------------------------
// Split-bf16 MFMA GEMM (fp32-accuracy): C = (Ah+Al) x (Bh+Bl)^T, dropping
// Al*Bl. Output as hi/lo bf16 split. 128x128 tile, BK=32.
// ---------------------------------------------------------------------------
__global__ __launch_bounds__(256) void gemm_split(const ushort_t* __restrict__ Ah,
                                                  const ushort_t* __restrict__ Al,
                                                  const ushort_t* __restrict__ Bh,
                                                  const ushort_t* __restrict__ Bl,
                                                  ushort_t* __restrict__ Chi,
                                                  ushort_t* __restrict__ Clo,
                                                  int M, int N, int Kd)
{
    __shared__ ushort_t AsH[128 * 40];
    __shared__ ushort_t AsL[128 * 40];
    __shared__ ushort_t BsH[128 * 40];
    __shared__ ushort_t BsL[128 * 40];
    const int tid = threadIdx.x;
    const int m0 = blockIdx.y * 128, n0 = blockIdx.x * 128;
    const int lane = tid & 63, w = tid >> 6;
    const int wm = (w & 1) * 64, wn = (w >> 1) * 64;
    const int ll = lane & 15, lh = lane >> 4;
    const int srow = tid >> 2, sk = (tid & 3) * 8;

    f32x4 acc[4][4];
#pragma unroll
    for (int i = 0; i < 4; i++)
#pragma unroll
        for (int j = 0; j < 4; j++) acc[i][j] = f32x4{0.f, 0.f, 0.f, 0.f};

    const size_t aoff = (size_t)(m0 + srow) * Kd + sk;
    const size_t boff = (size_t)(n0 + srow) * Kd + sk;
    const size_t roff = (size_t)64 * Kd;

    for (int k0 = 0; k0 < Kd; k0 += 32) {
        uint4 avh0 = *(const uint4*)(Ah + aoff + k0);
        uint4 avh1 = *(const uint4*)(Ah + aoff + k0 + roff);
        uint4 avl0 = *(const uint4*)(Al + aoff + k0);
        uint4 avl1 = *(const uint4*)(Al + aoff + k0 + roff);
        uint4 bvh0 = *(const uint4*)(Bh + boff + k0);
        uint4 bvh1 = *(const uint4*)(Bh + boff + k0 + roff);
        uint4 bvl0 = *(const uint4*)(Bl + boff + k0);
        uint4 bvl1 = *(const uint4*)(Bl + boff + k0 + roff);
        __syncthreads();
        *(uint4*)&AsH[srow * 40 + sk]        = avh0;
        *(uint4*)&AsH[(srow + 64) * 40 + sk] = avh1;
        *(uint4*)&AsL[srow * 40 + sk]        = avl0;
        *(uint4*)&AsL[(srow + 64) * 40 + sk] = avl1;
        *(uint4*)&BsH[srow * 40 + sk]        = bvh0;
        *(uint4*)&BsH[(srow + 64) * 40 + sk] = bvh1;
        *(uint4*)&BsL[srow * 40 + sk]        = bvl0;
        *(uint4*)&BsL[(srow + 64) * 40 + sk] = bvl1;
        __syncthreads();

        bf16x8 afh[4], afl[4], bfh[4], bfl[4];
#pragma unroll
        for (int i = 0; i < 4; i++) {
            afh[i] = *(const bf16x8*)&AsH[(wm + 16 * i + ll) * 40 + lh * 8];
            afl[i] = *(const bf16x8*)&AsL[(wm + 16 * i + ll) * 40 + lh * 8];
        }
#pragma unroll
        for (int j = 0; j < 4; j++) {
            bfh[j] = *(const bf16x8*)&BsH[(wn + 16 * j + ll) * 40 + lh * 8];
            bfl[j] = *(const bf16x8*)&BsL[(wn + 16 * j + ll) * 40 + lh * 8];
        }
#pragma unroll
        for (int i = 0; i < 4; i++)
#pragma unroll
            for (int j = 0; j < 4; j++) {
                acc[i][j] = __builtin_amdgcn_mfma_f32_16x16x32_bf16(afh[i], bfh[j], acc[i][j], 0, 0, 0);
                acc[i][j] = __builtin_amdgcn_mfma_f32_16x16x32_bf16(afh[i], bfl[j], acc[i][j], 0, 0, 0);
                acc[i][j] = __builtin_amdgcn_mfma_f32_16x16x32_bf16(afl[i], bfh[j], acc[i][j], 0, 0, 0);
            }
    }
#pragma unroll
    for (int i = 0; i < 4; i++)
#pragma unroll
        for (int j = 0; j < 4; j++)
#pragma unroll
            for (int r = 0; r < 4; r++) {
                float v = acc[i][j][r];
                ushort_t h = f2bf(v);
                ushort_t l = f2bf(v - bf2f(h));
                size_t idx = (size_t)(m0 + wm + 16 * i + lh * 4 + r) * N + (n0 + wn + 16 * j + ll);
                Chi[idx] = h;
                Clo[idx] = l;
            }
}

// ---------------------------------------------------------------------------
// Plain bf16 MFMA GEMM -> fp32 C (O projection)
// ---------------------------------------------------------------------------
__global__ __launch_bounds__(256) void gemm_bf16t(const ushort_t* __restrict__ A,
                                                  const ushort_t* __restrict__ Bt,
                                                  float* __restrict__ C,
                                                  int M, int N, int Kd)
{
    __shared__ ushort_t As[128 * 40];
    __shared__ ushort_t Bs[128 * 40];
    const int tid = threadIdx.x;
    const int m0 = blockIdx.y * 128, n0 = blockIdx.x * 128;
    const int lane = tid & 63, w = tid >> 6;
    const int wm = (w & 1) * 64, wn = (w >> 1) * 64;
    const int ll = lane & 15, lh = lane >> 4;
    const int srow = tid >> 2, sk = (tid & 3) * 8;

    f32x4 acc[4][4];
#pragma unroll
    for (int i = 0; i < 4; i++)
#pragma unroll
        for (int j = 0; j < 4; j++) acc[i][j] = f32x4{0.f, 0.f, 0.f, 0.f};

    const ushort_t* Ap = A + (size_t)(m0 + srow) * Kd + sk;
    const ushort_t* Bp = Bt + (size_t)(n0 + srow) * Kd + sk;

    for (int k0 = 0; k0 < Kd; k0 += 32) {
        uint4 av0 = *(const uint4*)(Ap + k0);
        uint4 av1 = *(const uint4*)(Ap + k0 + (size_t)64 * Kd);
        uint4 bv0 = *(const uint4*)(Bp + k0);
        uint4 bv1 = *(const uint4*)(Bp + k0 + (size_t)64 * Kd);
        __syncthreads();
        *(uint4*)&As[srow * 40 + sk]        = av0;
        *(uint4*)&As[(srow + 64) * 40 + sk] = av1;
        *(uint4*)&Bs[srow * 40 + sk]        = bv0;
        *(uint4*)&Bs[(srow + 64) * 40 + sk] = bv1;
        __syncthreads();

        bf16x8 af[4], bfr[4];
#pragma unroll
        for (int i = 0; i < 4; i++)
            af[i] = *(const bf16x8*)&As[(wm + 16 * i + ll) * 40 + lh * 8];
#pragma unroll
        for (int j = 0; j < 4; j++)
            bfr[j] = *(const bf16x8*)&Bs[(wn + 16 * j + ll) * 40 + lh * 8];
#pragma unroll
        for (int i = 0; i < 4; i++)
#pragma unroll
            for (int j = 0; j < 4; j++)
                acc[i][j] = __builtin_amdgcn_mfma_f32_16x16x32_bf16(af[i], bfr[j], acc[i][j], 0, 0, 0);
    }
#pragma unroll
    for (int i = 0; i < 4; i++)
#pragma unroll
        for (int j = 0; j < 4; j++)
#pragma unroll
            for (int r = 0; r < 4; r++)
                C[(size_t)(m0 + wm + 16 * i + lh * 4 + r) * N + (n0 + wn + 16 * j + ll)] = acc[i][j][r];
}

// ---------------------------------------------------------------------------
// Plain bf16 MFMA GEMM -> bf16 C^T  (V projection, writes Vt[e][s] directly)
// ---------------------------------------------------------------------------
__global__ __launch_bounds__(256) void gemm_bf16_vt(const ushort_t* __restrict__ A,
                                                    const ushort_t* __restrict__ Bt,
                                                    ushort_t* __restrict__ Ct,
                                                    int M, int N, int Kd)
{
    __shared__ ushort_t As[128 * 40];
    __shared__ ushort_t Bs[128 * 40];
    const int tid = threadIdx.x;
    const int m0 = blockIdx.y * 128, n0 = blockIdx.x * 128;
    const int lane = tid & 63, w = tid >> 6;
    const int wm = (w & 1) * 64, wn = (w >> 1) * 64;
    const int ll = lane & 15, lh = lane >> 4;
    const int srow = tid >> 2, sk = (tid & 3) * 8;

    f32x4 acc[4][4];
#pragma unroll
    for (int i = 0; i < 4; i++)
#pragma unroll
        for (int j = 0; j < 4; j++) acc[i][j] = f32x4{0.f, 0.f, 0.f, 0.f};

    const ushort_t* Ap = A + (size_t)(m0 + srow) * Kd + sk;
    const ushort_t* Bp = Bt + (size_t)(n0 + srow) * Kd + sk;

    for (int k0 = 0; k0 < Kd; k0 += 32) {
        uint4 av0 = *(const uint4*)(Ap + k0);
        uint4 av1 = *(const uint4*)(Ap + k0 + (size_t)64 * Kd);
        uint4 bv0 = *(const uint4*)(Bp + k0);
        uint4 bv1 = *(const uint4*)(Bp + k0 + (size_t)64 * Kd);
        __syncthreads();
        *(uint4*)&As[srow * 40 + sk]        = av0;
        *(uint4*)&As[(srow + 64) * 40 + sk] = av1;
        *(uint4*)&Bs[srow * 40 + sk]        = bv0;
        *(uint4*)&Bs[(srow + 64) * 40 + sk] = bv1;
        __syncthreads();

        bf16x8 af[4], bfr[4];
#pragma unroll
        for (int i = 0; i < 4; i++)
            af[i] = *(const bf16x8*)&As[(wm + 16 * i + ll) * 40 + lh * 8];
#pragma unroll
        for (int j = 0; j < 4; j++)
            bfr[j] = *(const bf16x8*)&Bs[(wn + 16 * j + ll) * 40 + lh * 8];
#pragma unroll
        for (int i = 0; i < 4; i++)
#pragma unroll
            for (int j = 0; j < 4; j++)
                acc[i][j] = __builtin_amdgcn_mfma_f32_16x16x32_bf16(af[i], bfr[j], acc[i][j], 0, 0, 0);
    }
#pragma unroll
    for (int i = 0; i < 4; i++)
#pragma unroll
        for (int j = 0; j < 4; j++) {
            ushort_t o4[4];
#pragma unroll
            for (int r = 0; r < 4; r++) o4[r] = f2bf(acc[i][j][r]);
            size_t n = n0 + wn + 16 * j + ll;
            size_t m = m0 + wm + 16 * i + lh * 4;
            *(uint2*)&Ct[n * M + m] = *(uint2*)o4;
        }
}

// ---------------------------------------------------------------------------
// RoPE from hi/lo split Q/K -> bf16 QR/KR
// ---------------------------------------------------------------------------
__global__ __launch_bounds__(256) void rope_split(const ushort_t* __restrict__ Qh,
                                                  const ushort_t* __restrict__ Ql,
                                                  const ushort_t* __restrict__ Kh,
                                                  const ushort_t* __restrict__ Kl,
                                                  ushort_t* __restrict__ QR,
                                                  ushort_t* __restrict__ KR)
{
    int idx = blockIdx.x * 256 + threadIdx.x;
    int s   = idx >> 11;
    int rem = idx & 2047;
    int h   = rem >> 6;
    int d   = rem & 63;
    float inv = exp2f(-0.20762050593046f * (float)d);
    float ang = (float)s * inv;
    float sn, cs;
    sincosf(ang, &sn, &cs);
    size_t base = (size_t)s * E + h * HD;
    float q0 = bf2f(Qh[base + d])      + bf2f(Ql[base + d]);
    float q1 = bf2f(Qh[base + d + 64]) + bf2f(Ql[base + d + 64]);
    QR[base + d]      = f2bf(q0 * cs - q1 * sn);
    QR[base + d + 64] = f2bf(q1 * cs + q0 * sn);
    float k0 = bf2f(Kh[base + d])      + bf2f(Kl[base + d]);
    float k1 = bf2f(Kh[base + d + 64]) + bf2f(Kl[base + d + 64]);
    KR[base + d]      = f2bf(k0 * cs - k1 * sn);
    KR[base + d + 64] = f2bf(k1 * cs + k0 * sn);
}

// ---------------------------------------------------------------------------
// Selection v4: 16 q-rows/block, 4 waves, u16 scores in LDS (68 KB -> 2
// blocks/CU). Score phase: split-bf16 3-MFMA, K A-frags direct from global,
// NO barriers/chunk. 2-pass radix on u16; exact tie-break among the
// threshold bucket via fp32 recompute (rare), demoting losers in LDS so
// mask phase keeps exactly NKEEP.
// ---------------------------------------------------------------------------
__global__ __launch_bounds__(256) void select_u16(const ushort_t* __restrict__ Qhi,
                                                  const ushort_t* __restrict__ Qlo,
                                                  const ushort_t* __restrict__ Khi,
                                                  const ushort_t* __restrict__ Klo,
                                                  unsigned* __restrict__ Mask)
{
    __shared__ ushort_t sc16[16 * 2048];   // 64 KB; 8B-block xor-swizzle per row
    __shared__ unsigned hist[4][256];      // 4 KB; reused as tie-col list

    const int tid = threadIdx.x;
    const int w = tid >> 6, lane = tid & 63;
    const int ll = lane & 15, lh = lane >> 4;
    const int q0 = blockIdx.x * 16;
    const int h  = blockIdx.y;

    // Q B-frags for rows q0+ll (hi/lo)
    bf16x8 bqh[4], bql[4];
    {
        const size_t qb = (size_t)(q0 + ll) * E + h * HD;
#pragma unroll
        for (int ks = 0; ks < 4; ks++) {
            bqh[ks] = *(const bf16x8*)&Qhi[qb + ks * 32 + lh * 8];
            bql[ks] = *(const bf16x8*)&Qlo[qb + ks * 32 + lh * 8];
        }
    }
    {   // zero scores (cols > qrow must read 0 = masked sentinel)
        uint4* sv = (uint4*)sc16;
        uint4 z = make_uint4(0u, 0u, 0u, 0u);
        for (int i = tid; i < 4096; i += 256) sv[i] = z;
    }
    __syncthreads();

    // ---- score phase (no barriers): wave w covers kv strip [cb+16w, +16) ----
    const int qend = q0 + 16;
    for (int cb = 0; cb < qend; cb += 64) {
        const size_t kbase = (size_t)(cb + w * 16 + ll) * E + h * HD;
        f32x4 acc = f32x4{0.f, 0.f, 0.f, 0.f};
#pragma unroll
        for (int ks = 0; ks < 4; ks++) {
            bf16x8 akh = *(const bf16x8*)&Khi[kbase + ks * 32 + lh * 8];
            bf16x8 akl = *(const bf16x8*)&Klo[kbase + ks * 32 + lh * 8];
            acc = __builtin_amdgcn_mfma_f32_16x16x32_bf16(akh, bqh[ks], acc, 0, 0, 0);
            acc = __builtin_amdgcn_mfma_f32_16x16x32_bf16(akh, bql[ks], acc, 0, 0, 0);
            acc = __builtin_amdgcn_mfma_f32_16x16x32_bf16(akl, bqh[ks], acc, 0, 0, 0);
        }
        // C-layout: q col = ll, kv row = w*16 + lh*4 + r
        const int qrow_g = q0 + ll;
        const int col0 = cb + w * 16 + lh * 4;
        ushort_t v4[4];
#pragma unroll
        for (int r = 0; r < 4; r++) {
            int col = col0 + r;
            v4[r] = (col <= qrow_g) ? (ushort_t)(fmap(acc[r]) >> 16) : (ushort_t)0;
        }
        const int blk = col0 >> 2;
        *(uint2*)&sc16[ll * 2048 + ((blk ^ (ll & 7)) << 2)] = *(uint2*)v4;
    }
    __syncthreads();

    // ---- radix + tie + mask: wave w owns q-rows 4w..4w+3 ----
    unsigned* hw = hist[w];
    for (int t = 0; t < 4; t++) {
        const int qq = w * 4 + t;
        const int qrow = q0 + qq;
        ushort_t* srow = &sc16[qq * 2048];
        const int swz = qq & 7;
        unsigned thr = 1u;
        if (qrow + 1 > NKEEP) {
            unsigned p = 0u, need = NKEEP;
#pragma unroll
            for (int pass = 0; pass < 2; pass++) {
                const int shift = 8 - 8 * pass;
                *(uint4*)&hw[lane * 4] = make_uint4(0u, 0u, 0u, 0u);
                __threadfence_block();
                for (int i = 0; i < 32; i++) {
                    unsigned v = srow[lane + (i << 6)];   // order-agnostic: read swizzled
                    bool part = (pass == 0) || ((v >> 8) == p);
                    if (part) atomicAdd(&hw[(v >> shift) & 255u], 1u);
                }
                __threadfence_block();
                uint4 hv = *(const uint4*)&hw[lane * 4];
                unsigned t3 = hv.w, t2 = t3 + hv.z, t1 = t2 + hv.y, t0 = t1 + hv.x;
                unsigned sv = t0, run = sv;
#pragma unroll
                for (int off = 1; off < 64; off <<= 1) {
                    unsigned o = __shfl_down(run, off);
                    if (lane + off < 64) run += o;
                }
                const unsigned nxt = run - sv;
                unsigned tj[4] = { t0, t1, t2, t3 };
                bool m = false; unsigned nb = 0u, nn = 0u;
#pragma unroll
                for (int j = 0; j < 4; j++) {
                    unsigned sb  = nxt + tj[j];
                    unsigned sb1 = nxt + ((j < 3) ? tj[j + 1] : 0u);
                    if (!m && need <= sb && need > sb1) {
                        m = true; nb = (unsigned)(lane * 4 + j); nn = need - sb1;
                    }
                }
                unsigned long long bal = __ballot(m);
                int src = __ffsll(bal) - 1;
                p    = (p << 8) | __shfl(nb, src);
                need = __shfl(nn, src);
            }
            thr = p;
            const unsigned count_eq = hw[p & 255u];   // pass-2 hist persists
            const unsigned t_need = need;
            if (count_eq > t_need) {
                const bool ovf = (count_eq > 64);
                ushort_t* tiecol = (ushort_t*)hw;     // hist no longer needed
                unsigned tcnt = 0;
                for (int i = 0; i < 32; i++) {
                    int c = lane + (i << 6);
                    int adr = (((c >> 2) ^ swz) << 2) | (c & 3);
                    bool eq = (srow[adr] == (ushort_t)thr);
                    unsigned long long bal = __ballot(eq);
                    if (eq) {
                        unsigned slot = tcnt + (unsigned)__popcll(bal & ((1ull << lane) - 1ull));
                        if (ovf) {
                            if (slot >= t_need) srow[adr] = (ushort_t)(thr - 1u);  // keep-first-by-col fallback
                        } else {
                            tiecol[slot] = (ushort_t)c;
                        }
                    }
                    tcnt += (unsigned)__popcll(bal);
                }
                if (!ovf) {
                    __threadfence_block();
                    const int ntie = (int)count_eq;
                    int mycol = (lane < ntie) ? (int)tiecol[lane] : 0;
                    float myval = 0.f;
                    const size_t qb = (size_t)qrow * E + h * HD;
                    const float qv0 = bf2f(Qhi[qb + lane])      + bf2f(Qlo[qb + lane]);
                    const float qv1 = bf2f(Qhi[qb + lane + 64]) + bf2f(Qlo[qb + lane + 64]);
                    for (int tt = 0; tt < ntie; tt++) {
                        const size_t kb = (size_t)tiecol[tt] * E + h * HD;
                        float kv0 = bf2f(Khi[kb + lane])      + bf2f(Klo[kb + lane]);
                        float kv1 = bf2f(Khi[kb + lane + 64]) + bf2f(Klo[kb + lane + 64]);
                        float pp = qv0 * kv0 + qv1 * kv1;
#pragma unroll
                        for (int off = 1; off < 64; off <<= 1) pp += __shfl_xor(pp, off);
                        if (lane == tt) myval = pp;
                    }
                    int rank = 0;
                    for (int j = 0; j < ntie; j++) {
                        float vj = __shfl(myval, j);
                        int   cj = __shfl(mycol, j);
                        if (lane < ntie && ((vj > myval) || (vj == myval && cj < mycol))) rank++;
                    }
                    if (lane < ntie && rank >= (int)t_need) {
                        int adr = (((mycol >> 2) ^ swz) << 2) | (mycol & 3);
                        srow[adr] = (ushort_t)(thr - 1u);
                    }
                    __threadfence_block();
                }
            }
        }
        // mask write: keep = score >= thr (exactly NKEEP kept for radix rows)
        const size_t mbase = ((size_t)h * S + qrow) * 64;
        for (int base = 0; base < S; base += 64) {
            int c = base + lane;
            int adr = (((c >> 2) ^ swz) << 2) | (c & 3);
            bool keep = (unsigned)srow[adr] >= thr;
            unsigned long long bm = __ballot(keep);
            if (lane == 0) {
                Mask[mbase + (base >> 5)]     = (unsigned)bm;
                Mask[mbase + (base >> 5) + 1] = (unsigned)(bm >> 32);
            }
        }
    }
}

// ---------------------------------------------------------------------------
// MFMA flash attention (unchanged from R3/R4)
// ---------------------------------------------------------------------------
__global__ __launch_bounds__(256) void attn_mfma(const ushort_t* __restrict__ QR,
                                                 const ushort_t* __restrict__ KR,
                                                 const ushort_t* __restrict__ Vt,
                                                 const unsigned* __restrict__ Mask,
                                                 ushort_t* __restrict__ O)
{
    __shared__ ushort_t Qs[64][136];
    __shared__ ushort_t Ks[64][136];
    __shared__ ushort_t Vs[128][72];
    __shared__ unsigned long long Ms[64];

    const int tid = threadIdx.x;
    const int w = tid >> 6, lane = tid & 63;
    const int ll = lane & 15, lh = lane >> 4;
    const int q0 = blockIdx.x * 64;
    const int h  = blockIdx.y;

#pragma unroll
    for (int i = 0; i < 4; i++) {
        int idx = tid + i * 256;
        int r = idx >> 4, c8 = (idx & 15) * 8;
        *(uint4*)&Qs[r][c8] = *(const uint4*)&QR[(size_t)(q0 + r) * E + h * HD + c8];
    }

    f32x4 Oa[8];
#pragma unroll
    for (int i = 0; i < 8; i++) Oa[i] = f32x4{0.f, 0.f, 0.f, 0.f};
    float mrun = NEGF, lrun = 0.f;
    const float SCL = 0.08838834764831845f * 1.44269504088896f;

    for (int cb = 0; cb <= q0; cb += 64) {
        __syncthreads();
#pragma unroll
        for (int i = 0; i < 4; i++) {
            int idx = tid + i * 256;
            int r = idx >> 4, c8 = (idx & 15) * 8;
            *(uint4*)&Ks[r][c8] = *(const uint4*)&KR[(size_t)(cb + r) * E + h * HD + c8];
        }
#pragma unroll
        for (int i = 0; i < 4; i++) {
            int idx = tid + i * 256;
            int r = idx >> 3, c8 = (idx & 7) * 8;
            *(uint4*)&Vs[r][c8] = *(const uint4*)&Vt[((size_t)h * HD + r) * S + cb + c8];
        }
        if (tid < 64)
            Ms[tid] = *(const unsigned long long*)&Mask[((size_t)h * S + q0 + tid) * 64 + (cb >> 5)];
        __syncthreads();

        f32x4 Sc[4];
#pragma unroll
        for (int t = 0; t < 4; t++) Sc[t] = f32x4{0.f, 0.f, 0.f, 0.f};
#pragma unroll
        for (int kk = 0; kk < 4; kk++) {
            bf16x8 bq = *(const bf16x8*)&Qs[16 * w + ll][kk * 32 + lh * 8];
#pragma unroll
            for (int t = 0; t < 4; t++) {
                bf16x8 ak = *(const bf16x8*)&Ks[t * 16 + ll][kk * 32 + lh * 8];
                Sc[t] = __builtin_amdgcn_mfma_f32_16x16x32_bf16(ak, bq, Sc[t], 0, 0, 0);
            }
        }

        unsigned long long mrow = Ms[16 * w + ll];
        float sc[4][4];
        float cm = NEGF;
#pragma unroll
        for (int t = 0; t < 4; t++)
#pragma unroll
            for (int r = 0; r < 4; r++) {
                int bit = t * 16 + lh * 4 + r;
                float v = ((mrow >> bit) & 1ull) ? Sc[t][r] * SCL : NEGF;
                sc[t][r] = v;
                cm = fmaxf(cm, v);
            }
        cm = fmaxf(cm, __shfl_xor(cm, 16));
        cm = fmaxf(cm, __shfl_xor(cm, 32));
        float mnew = fmaxf(mrun, cm);
        float alpha = exp2f(mrun - mnew);
        mrun = mnew;
        lrun *= alpha;

        unsigned pk[4][2];
#pragma unroll
        for (int t = 0; t < 4; t++) {
            float p0 = (sc[t][0] > -1e37f) ? exp2f(sc[t][0] - mnew) : 0.f;
            float p1 = (sc[t][1] > -1e37f) ? exp2f(sc[t][1] - mnew) : 0.f;
            float p2 = (sc[t][2] > -1e37f) ? exp2f(sc[t][2] - mnew) : 0.f;
            float p3 = (sc[t][3] > -1e37f) ? exp2f(sc[t][3] - mnew) : 0.f;
            lrun += p0 + p1 + p2 + p3;
            pk[t][0] = (unsigned)f2bf(p0) | ((unsigned)f2bf(p1) << 16);
            pk[t][1] = (unsigned)f2bf(p2) | ((unsigned)f2bf(p3) << 16);
        }
#pragma unroll
        for (int dt = 0; dt < 8; dt++) Oa[dt] *= alpha;

#pragma unroll
        for (int ks = 0; ks < 2; ks++) {
            union { unsigned u[4]; bf16x8 v; } bu;
#pragma unroll
            for (int jj = 0; jj < 4; jj++) {
                int rp  = jj & 1;
                int src = ll + 16 * ((lh & 1) * 2 + (jj >> 1));
                unsigned v0 = __shfl(pk[ks * 2][rp], src);
                unsigned v1 = __shfl(pk[ks * 2 + 1][rp], src);
                bu.u[jj] = (lh >> 1) ? v1 : v0;
            }
            bf16x8 bp = bu.v;
#pragma unroll
            for (int dt = 0; dt < 8; dt++) {
                bf16x8 av = *(const bf16x8*)&Vs[dt * 16 + ll][ks * 32 + lh * 8];
                Oa[dt] = __builtin_amdgcn_mfma_f32_16x16x32_bf16(av, bp, Oa[dt], 0, 0, 0);
            }
        }
    }

    lrun += __shfl_xor(lrun, 16);
    lrun += __shfl_xor(lrun, 32);
    float linv = 1.0f / lrun;

    __syncthreads();
    ushort_t* tb = &Ks[16 * w][0];
#pragma unroll
    for (int dt = 0; dt < 8; dt++)
#pragma unroll
        for (int r = 0; r < 4; r++)
            tb[ll * 136 + dt * 16 + lh * 4 + r] = f2bf(Oa[dt][r] * linv);
#pragma unroll
    for (int i = 0; i < 4; i++) {
        int idx = lane + 64 * i;
        int r = idx >> 4, c8 = (idx & 15) * 8;
        uint4 vv = *(const uint4*)&tb[r * 136 + c8];
        *(uint4*)&O[(size_t)(q0 + 16 * w + r) * E + h * HD + c8] = vv;
    }
}

// ---------------------------------------------------------------------------
extern "C" void kernel_launch(void* const* d_in, const int* in_sizes, int n_in,
                              void* d_out, int out_size, void* d_ws, size_t ws_size,
                              hipStream_t stream)
{
    (void)in_sizes; (void)n_in; (void)out_size; (void)ws_size;
    const float* hidden = (const float*)d_in[0];
    const float* Wq = (const float*)d_in[1];
    const float* Wk = (const float*)d_in[2];
    const float* Wv = (const float*)d_in[3];
    const float* Wo = (const float*)d_in[4];

    float* ws = (float*)d_ws;
    const size_t SE = (size_t)S * E;   // 8388608
    ushort_t* Hhi  = (ushort_t*)ws;                      // [0,   .5SE)
    ushort_t* Hlo  = (ushort_t*)(ws + SE / 2);           // [.5,  1SE)  -> later Obf
    ushort_t* WtH  = (ushort_t*)(ws + SE);               // [1,   2SE)  -> later Wt
    ushort_t* WtL  = (ushort_t*)(ws + 2 * SE);           // [2,   3SE)  -> later QR/KR
    ushort_t* Qhi  = (ushort_t*)(ws + 3 * SE);           // [3,  3.5SE)
    ushort_t* Qlo  = (ushort_t*)(ws + 3 * SE + SE / 2);  // [3.5, 4SE)
    ushort_t* Khi  = (ushort_t*)(ws + 4 * SE);           // [4,  4.5SE)
    ushort_t* Klo  = (ushort_t*)(ws + 4 * SE + SE / 2);  // [4.5, 5SE)
    unsigned* Maskb= (unsigned*)(ws + 5 * SE);           // [5,  5.5SE)
    ushort_t* Vtbf = (ushort_t*)(ws + 5 * SE + SE / 2);  // [5.5, 6SE)
    ushort_t* QRbf = WtL;
    ushort_t* KRbf = (ushort_t*)(ws + 2 * SE + SE / 2);
    ushort_t* Obf  = Hlo;
    ushort_t* Wt   = WtH;
    // total = 6 SE floats = 201 MB

    dim3 gg(E / 128, S / 128);           // (32,16)
    dim3 gt(E / 32, E / 32);             // (128,128)

    decomp<<<SE / 2048, 256, 0, stream>>>(hidden, Hhi, Hlo);

    transp_decomp<<<gt, 256, 0, stream>>>(Wq, WtH, WtL);
    gemm_split<<<gg, 256, 0, stream>>>(Hhi, Hlo, WtH, WtL, Qhi, Qlo, S, E, E);
    transp_decomp<<<gt, 256, 0, stream>>>(Wk, WtH, WtL);
    gemm_split<<<gg, 256, 0, stream>>>(Hhi, Hlo, WtH, WtL, Khi, Klo, S, E, E);

    select_u16<<<dim3(S / 16, H), 256, 0, stream>>>(Qhi, Qlo, Khi, Klo, Maskb);

    rope_split<<<(S * 2048) / 256, 256, 0, stream>>>(Qhi, Qlo, Khi, Klo, QRbf, KRbf);

    transp_cvt<<<gt, 256, 0, stream>>>(Wv, Wt);
    gemm_bf16_vt<<<gg, 256, 0, stream>>>(Hhi, Wt, Vtbf, S, E, E);

    attn_mfma<<<dim3(S / 64, H), 256, 0, stream>>>(QRbf, KRbf, Vtbf, Maskb, Obf);

    transp_cvt<<<gt, 256, 0, stream>>>(Wo, Wt);
    gemm_bf16t<<<gg, 256, 0, stream>>>(Obf, Wt, (float*)d_out, S, E, E);
}